// Round 8
// baseline (348.232 us; speedup 1.0000x reference)
//
#include <hip/hip_runtime.h>
#include <hip/hip_bf16.h>

#define S_  2048
#define DM_ 512
#define H_  8
#define DH_ 64
#define MF_ 64
#define DFF_ 2048
#define L_  2
#define CT_ 64
#define NC_ (S_ / CT_)
#define EPS_ 1e-6f
#define LN_EPS_ 1e-5f

#define LSW_   3145728
#define W1OFF_ 1048576
#define W2OFF_ 2097152
#define WOOFF_ 786432

typedef unsigned short ushortT;
typedef unsigned int u32;
typedef float f4 __attribute__((ext_vector_type(4)));
typedef short s8 __attribute__((ext_vector_type(8)));
typedef u32 u32x2 __attribute__((ext_vector_type(2)));

__device__ __forceinline__ ushortT f2b(float f) {
  union { float f; unsigned u; } v; v.f = f;
  unsigned r = v.u + 0x7fffu + ((v.u >> 16) & 1u);  // RNE
  return (ushortT)(r >> 16);
}
__device__ __forceinline__ float bu2f(ushortT h) {
  union { unsigned u; float f; } v; v.u = ((unsigned)h) << 16; return v.f;
}
__device__ __forceinline__ u32 pk2(float a, float b) {
  return (u32)f2b(a) | ((u32)f2b(b) << 16);
}

// ---------------------------------------------------------------- fused setup
// flat grid: [0,2048) QKVO transpose, [2048,4096) W1, [4096,6144) W2,
// [6144,6152) omega, [6152,10248) copy_in, 10248 = flag zero
__global__ __launch_bounds__(256) void tcast_all(
    const float* __restrict__ x,
    const float* __restrict__ Wq, const float* __restrict__ Wk,
    const float* __restrict__ Wv, const float* __restrict__ Wo,
    const float* __restrict__ W1, const float* __restrict__ W2,
    const float* __restrict__ omg,
    float* __restrict__ cur, ushortT* __restrict__ curb,
    ushortT* __restrict__ wb, ushortT* __restrict__ omgTb,
    u32* __restrict__ flags) {
  const int bid = blockIdx.x;
  const int t = threadIdx.x;
  if (bid == 10248) {  // zero lookback flags (2 layers x 256)
    flags[t] = 0u;
    flags[t + 256] = 0u;
    return;
  }
  if (bid >= 6152) {  // copy_in
    const int i = (bid - 6152) * 256 + t;
    float v = x[i];
    cur[i] = v;
    curb[i] = f2b(v);
    return;
  }
  __shared__ ushortT tile[32][33];
  const float* src; ushortT* dst; int K, N, bx, by;
  if (bid < 2048) {
    const int z = bid >> 8, widx = z & 3, lay = z >> 2;
    const float* s4[4] = {Wq, Wk, Wv, Wo};
    src = s4[widx] + (size_t)lay * DM_ * DM_;
    dst = wb + (size_t)lay * LSW_ + (size_t)widx * DM_ * DM_;
    K = DM_; N = DM_; bx = bid & 15; by = (bid >> 4) & 15;
  } else if (bid < 4096) {
    const int r = bid - 2048;
    const int lay = r >> 10;
    src = W1 + (size_t)lay * DM_ * DFF_;
    dst = wb + (size_t)lay * LSW_ + W1OFF_;
    K = DM_; N = DFF_; bx = r & 63; by = (r >> 6) & 15;
  } else if (bid < 6144) {
    const int r = bid - 4096;
    const int lay = r >> 10;
    src = W2 + (size_t)lay * DFF_ * DM_;
    dst = wb + (size_t)lay * LSW_ + W2OFF_;
    K = DFF_; N = DM_; bx = r & 15; by = (r >> 4) & 63;
  } else {
    const int r = bid - 6144;
    const int lay = r >> 2;
    src = omg + (size_t)lay * DH_ * MF_;
    dst = omgTb + (size_t)lay * DH_ * MF_;
    K = DH_; N = MF_; bx = r & 1; by = (r >> 1) & 1;
  }
  const int cc = t & 31, r0 = t >> 5;
  const int n0 = bx * 32, k0 = by * 32;
#pragma unroll
  for (int i = 0; i < 4; ++i) {
    int r = r0 + 8 * i;
    tile[r][cc] = f2b(src[(size_t)(k0 + r) * N + n0 + cc]);
  }
  __syncthreads();
#pragma unroll
  for (int i = 0; i < 4; ++i) {
    int r = r0 + 8 * i;
    dst[(size_t)(n0 + r) * K + k0 + cc] = tile[cc][r];
  }
}

// ---------------------------------------------------------------- MFMA GEMM (full-K)
template<bool RELU, bool HAS_RES, bool OUT_BF16>
__global__ __launch_bounds__(256) void mgemm(
    const ushortT* __restrict__ A, const ushortT* __restrict__ Wt,
    const float* __restrict__ bias, const float* __restrict__ Res,
    float* __restrict__ Cf, ushortT* __restrict__ Cb, int K, int N) {
  __shared__ ushortT sA[2][2048];
  __shared__ ushortT sB[2][2048];
  const int t = threadIdx.x;
  const int w = t >> 6, l = t & 63;
  const int wm = w >> 1, wn = w & 1;
  const int n0 = blockIdx.x * 64, m0 = blockIdx.y * 64;

  const int rs = w * 16 + (l >> 2);
  const int qs = (l & 3) ^ ((rs >> 1) & 3);
  const ushortT* gA = A  + (size_t)(m0 + rs) * K + qs * 8;
  const ushortT* gB = Wt + (size_t)(n0 + rs) * K + qs * 8;

  const int Ra = wm * 32 + (l & 15);
  const int Rb = wn * 32 + (l & 15);
  const int qq = l >> 4;
  const int aoff = (Ra * 4 + (qq ^ ((Ra >> 1) & 3))) * 8;
  const int boff = (Rb * 4 + (qq ^ ((Rb >> 1) & 3))) * 8;

  f4 acc[2][2];
#pragma unroll
  for (int i = 0; i < 2; ++i)
#pragma unroll
    for (int j = 0; j < 2; ++j) acc[i][j] = (f4){0.f, 0.f, 0.f, 0.f};

  auto stage = [&](int buf, int ko) {
    __builtin_amdgcn_global_load_lds(
        (const __attribute__((address_space(1))) void*)(gA + ko),
        (__attribute__((address_space(3))) void*)(&sA[buf][w * 512]), 16, 0, 0);
    __builtin_amdgcn_global_load_lds(
        (const __attribute__((address_space(1))) void*)(gB + ko),
        (__attribute__((address_space(3))) void*)(&sB[buf][w * 512]), 16, 0, 0);
  };

  stage(0, 0);
  const int nk = K >> 5;
  for (int ks = 0; ks < nk; ++ks) {
    __syncthreads();
    if (ks + 1 < nk) stage((ks + 1) & 1, (ks + 1) * 32);
    const ushortT* pa = sA[ks & 1];
    const ushortT* pb = sB[ks & 1];
    s8 a0 = *(const s8*)(pa + aoff);
    s8 a1 = *(const s8*)(pa + aoff + 512);
    s8 b0 = *(const s8*)(pb + boff);
    s8 b1 = *(const s8*)(pb + boff + 512);
    acc[0][0] = __builtin_amdgcn_mfma_f32_16x16x32_bf16(a0, b0, acc[0][0], 0, 0, 0);
    acc[0][1] = __builtin_amdgcn_mfma_f32_16x16x32_bf16(a0, b1, acc[0][1], 0, 0, 0);
    acc[1][0] = __builtin_amdgcn_mfma_f32_16x16x32_bf16(a1, b0, acc[1][0], 0, 0, 0);
    acc[1][1] = __builtin_amdgcn_mfma_f32_16x16x32_bf16(a1, b1, acc[1][1], 0, 0, 0);
  }

  const int colb = n0 + wn * 32 + (l & 15);
  const int rowb = m0 + wm * 32 + ((l >> 4) << 2);
#pragma unroll
  for (int mt = 0; mt < 2; ++mt) {
#pragma unroll
    for (int nt = 0; nt < 2; ++nt) {
      const int c = colb + nt * 16;
      const float bv = bias[c];
#pragma unroll
      for (int r = 0; r < 4; ++r) {
        const int rr = rowb + mt * 16 + r;
        float v = acc[mt][nt][r] + bv;
        if (HAS_RES) v += Res[(size_t)rr * N + c];
        if (RELU) v = fmaxf(v, 0.f);
        if (OUT_BF16) Cb[(size_t)rr * N + c] = f2b(v);
        else          Cf[(size_t)rr * N + c] = v;
      }
    }
  }
}

// ---------------------------------------------------------------- MFMA GEMM partial (split-K)
__global__ __launch_bounds__(256) void mgemm_part(
    const ushortT* __restrict__ A, const ushortT* __restrict__ Wt,
    float* __restrict__ PS, int K, int N, int KS) {
  __shared__ ushortT sA[2][2048];
  __shared__ ushortT sB[2][2048];
  const int t = threadIdx.x;
  const int w = t >> 6, l = t & 63;
  const int wm = w >> 1, wn = w & 1;
  const int n0 = blockIdx.x * 64, m0 = blockIdx.y * 64;
  const int z = blockIdx.z;

  const int rs = w * 16 + (l >> 2);
  const int qs = (l & 3) ^ ((rs >> 1) & 3);
  const ushortT* gA = A  + (size_t)(m0 + rs) * K + z * KS + qs * 8;
  const ushortT* gB = Wt + (size_t)(n0 + rs) * K + z * KS + qs * 8;

  const int Ra = wm * 32 + (l & 15);
  const int Rb = wn * 32 + (l & 15);
  const int qq = l >> 4;
  const int aoff = (Ra * 4 + (qq ^ ((Ra >> 1) & 3))) * 8;
  const int boff = (Rb * 4 + (qq ^ ((Rb >> 1) & 3))) * 8;

  f4 acc[2][2];
#pragma unroll
  for (int i = 0; i < 2; ++i)
#pragma unroll
    for (int j = 0; j < 2; ++j) acc[i][j] = (f4){0.f, 0.f, 0.f, 0.f};

  auto stage = [&](int buf, int ko) {
    __builtin_amdgcn_global_load_lds(
        (const __attribute__((address_space(1))) void*)(gA + ko),
        (__attribute__((address_space(3))) void*)(&sA[buf][w * 512]), 16, 0, 0);
    __builtin_amdgcn_global_load_lds(
        (const __attribute__((address_space(1))) void*)(gB + ko),
        (__attribute__((address_space(3))) void*)(&sB[buf][w * 512]), 16, 0, 0);
  };

  stage(0, 0);
  const int nk = KS >> 5;
  for (int ks = 0; ks < nk; ++ks) {
    __syncthreads();
    if (ks + 1 < nk) stage((ks + 1) & 1, (ks + 1) * 32);
    const ushortT* pa = sA[ks & 1];
    const ushortT* pb = sB[ks & 1];
    s8 a0 = *(const s8*)(pa + aoff);
    s8 a1 = *(const s8*)(pa + aoff + 512);
    s8 b0 = *(const s8*)(pb + boff);
    s8 b1 = *(const s8*)(pb + boff + 512);
    acc[0][0] = __builtin_amdgcn_mfma_f32_16x16x32_bf16(a0, b0, acc[0][0], 0, 0, 0);
    acc[0][1] = __builtin_amdgcn_mfma_f32_16x16x32_bf16(a0, b1, acc[0][1], 0, 0, 0);
    acc[1][0] = __builtin_amdgcn_mfma_f32_16x16x32_bf16(a1, b0, acc[1][0], 0, 0, 0);
    acc[1][1] = __builtin_amdgcn_mfma_f32_16x16x32_bf16(a1, b1, acc[1][1], 0, 0, 0);
  }

  float* out = PS + (size_t)z * S_ * N;
  const int colb = n0 + wn * 32 + (l & 15);
  const int rowb = m0 + wm * 32 + ((l >> 4) << 2);
#pragma unroll
  for (int mt = 0; mt < 2; ++mt) {
#pragma unroll
    for (int nt = 0; nt < 2; ++nt) {
      const int c = colb + nt * 16;
#pragma unroll
      for (int r = 0; r < 4; ++r)
        out[(size_t)(rowb + mt * 16 + r) * N + c] = acc[mt][nt][r];
    }
  }
}

// ---------------------------------------------------------------- reduce splits + bias + res + LN
__global__ __launch_bounds__(256) void redln(const float* __restrict__ PS, int nsplit,
                                             const float* __restrict__ bias,
                                             const float* __restrict__ res,
                                             const float* __restrict__ g,
                                             const float* __restrict__ be,
                                             float* __restrict__ outF,
                                             ushortT* __restrict__ outB) {
  const int s = blockIdx.x, t = threadIdx.x;
  float v0 = bias[t] + res[(size_t)s * DM_ + t];
  float v1 = bias[t + 256] + res[(size_t)s * DM_ + 256 + t];
  for (int z = 0; z < nsplit; ++z) {
    const float* p = PS + (size_t)z * S_ * DM_ + (size_t)s * DM_;
    v0 += p[t];
    v1 += p[256 + t];
  }
  float sum = v0 + v1, sq = v0 * v0 + v1 * v1;
  for (int off = 32; off > 0; off >>= 1) {
    sum += __shfl_down(sum, off);
    sq += __shfl_down(sq, off);
  }
  __shared__ float ssum[4], ssq[4];
  __shared__ float smean, srstd;
  const int w = t >> 6;
  if ((t & 63) == 0) { ssum[w] = sum; ssq[w] = sq; }
  __syncthreads();
  if (t == 0) {
    float S1 = ssum[0] + ssum[1] + ssum[2] + ssum[3];
    float S2 = ssq[0] + ssq[1] + ssq[2] + ssq[3];
    float mu = S1 / DM_;
    smean = mu;
    srstd = rsqrtf(S2 / DM_ - mu * mu + LN_EPS_);
  }
  __syncthreads();
  const float mu = smean, rs = srstd;
  float o0 = (v0 - mu) * rs * g[t] + be[t];
  float o1 = (v1 - mu) * rs * g[256 + t] + be[256 + t];
  outF[(size_t)s * DM_ + t] = o0;
  outF[(size_t)s * DM_ + 256 + t] = o1;
  if (outB) {
    outB[(size_t)s * DM_ + t] = f2b(o0);
    outB[(size_t)s * DM_ + 256 + t] = f2b(o1);
  }
}

// ---------------------------------------------------------------- fused attention mega-kernel
// Block (c,h): QKV tile GEMM -> LDS, FAVOR+chunk sums in LDS, publish chunk sums
// with release flag, decoupled-lookback exclusive prefix, Tm/den/numT -> Aout.
__global__ __launch_bounds__(256) void attn_mega(
    const ushortT* __restrict__ curb, const ushortT* __restrict__ wl,
    const float* __restrict__ bq, const float* __restrict__ bk,
    const float* __restrict__ bv, const ushortT* __restrict__ omgT,
    float* __restrict__ KVc, float* __restrict__ Kc,
    u32* __restrict__ flags, ushortT* __restrict__ Aout) {
  const int cc = blockIdx.x, h = blockIdx.y, t = threadIdx.x;
  const int w = t >> 6, l = t & 63, lr = l & 15, q = l >> 4;
  const int wm = w >> 1, wn = w & 1;

  __shared__ char smem[65536];
  ushortT* sA  = (ushortT*)smem;             // [2][2048]   (GEMM phase)
  ushortT* sB  = sA + 4096;                  // [2][3][2048]
  ushortT* xq  = (ushortT*)smem;             // 64*72 each (favor phase, aliases staging)
  ushortT* xk  = xq + 4608;
  ushortT* vT  = xk + 4608;
  ushortT* omT = vT + 4608;
  ushortT* pq  = omT + 4608;
  ushortT* pk  = pq + 4608;
  ushortT* pkT = pk + 4608;
  float* nrm = (float*)(smem + 64512);       // 128 floats
  float* den = (float*)(smem + 65024);       // 64
  float* kcs = (float*)(smem + 65280);       // 64
  ushortT* kvs = xq;                          // phase C aliases
  ushortT* tms = xk;

  // ================= phase G: QKV tile GEMM (A rows cc*64, W cols h*64) =================
  const int m0 = cc * 64, n0 = h * 64;
  const int rs = w * 16 + (l >> 2);
  const int qs2 = (l & 3) ^ ((rs >> 1) & 3);
  const ushortT* gA = curb + (size_t)(m0 + rs) * DM_ + qs2 * 8;
  const ushortT* gB = wl + (size_t)(n0 + rs) * DM_ + qs2 * 8;  // +z*DM*DM per weight

  const int Ra = wm * 32 + lr;
  const int Rb = wn * 32 + lr;
  const int aoff = (Ra * 4 + (q ^ ((Ra >> 1) & 3))) * 8;
  const int boff = (Rb * 4 + (q ^ ((Rb >> 1) & 3))) * 8;

  f4 acc[3][2][2];
#pragma unroll
  for (int z = 0; z < 3; ++z)
#pragma unroll
    for (int i = 0; i < 2; ++i)
#pragma unroll
      for (int j = 0; j < 2; ++j) acc[z][i][j] = (f4){0.f, 0.f, 0.f, 0.f};

  auto stage = [&](int buf, int ko) {
    __builtin_amdgcn_global_load_lds(
        (const __attribute__((address_space(1))) void*)(gA + ko),
        (__attribute__((address_space(3))) void*)(sA + buf * 2048 + w * 512), 16, 0, 0);
#pragma unroll
    for (int z = 0; z < 3; ++z)
      __builtin_amdgcn_global_load_lds(
          (const __attribute__((address_space(1))) void*)(gB + (size_t)z * DM_ * DM_ + ko),
          (__attribute__((address_space(3))) void*)(sB + buf * 6144 + z * 2048 + w * 512), 16, 0, 0);
  };

  stage(0, 0);
  for (int ks = 0; ks < 16; ++ks) {
    __syncthreads();
    if (ks + 1 < 16) stage((ks + 1) & 1, (ks + 1) * 32);
    const ushortT* pa = sA + (ks & 1) * 2048;
    s8 a0 = *(const s8*)(pa + aoff);
    s8 a1 = *(const s8*)(pa + aoff + 512);
#pragma unroll
    for (int z = 0; z < 3; ++z) {
      const ushortT* pb = sB + (ks & 1) * 6144 + z * 2048;
      s8 b0 = *(const s8*)(pb + boff);
      s8 b1 = *(const s8*)(pb + boff + 512);
      acc[z][0][0] = __builtin_amdgcn_mfma_f32_16x16x32_bf16(a0, b0, acc[z][0][0], 0, 0, 0);
      acc[z][0][1] = __builtin_amdgcn_mfma_f32_16x16x32_bf16(a0, b1, acc[z][0][1], 0, 0, 0);
      acc[z][1][0] = __builtin_amdgcn_mfma_f32_16x16x32_bf16(a1, b0, acc[z][1][0], 0, 0, 0);
      acc[z][1][1] = __builtin_amdgcn_mfma_f32_16x16x32_bf16(a1, b1, acc[z][1][1], 0, 0, 0);
    }
  }
  __syncthreads();  // all staging reads done; safe to overwrite with favor arrays

  // epilogue: bias + bf16 -> LDS (q/k straight, v transposed); load omT
  {
    const int colL = wn * 32 + lr;
    const int rowL = wm * 32 + q * 4;
#pragma unroll
    for (int mt = 0; mt < 2; ++mt) {
#pragma unroll
      for (int nt = 0; nt < 2; ++nt) {
        const int col = colL + nt * 16;
        const float bqv = bq[n0 + col], bkv = bk[n0 + col], bvv = bv[n0 + col];
#pragma unroll
        for (int r = 0; r < 4; ++r) {
          const int row = rowL + mt * 16 + r;
          xq[row * 72 + col] = f2b(acc[0][mt][nt][r] + bqv);
          xk[row * 72 + col] = f2b(acc[1][mt][nt][r] + bkv);
          vT[col * 72 + row] = f2b(acc[2][mt][nt][r] + bvv);
        }
      }
    }
    for (int i = t; i < 512; i += 256) {
      const int s = i >> 3, seg = i & 7;
      *(s8*)&omT[s * 72 + seg * 8] = *(const s8*)(omgT + s * 64 + seg * 8);
    }
  }
  __syncthreads();

  // ================= phase F: FAVOR =================
  if (t < 128) {
    const ushortT* src = (t < 64) ? xq : xk;
    const int s = t & 63;
    float a = 0.f;
#pragma unroll
    for (int seg = 0; seg < 8; ++seg) {
      s8 vv = *(const s8*)(src + s * 72 + seg * 8);
#pragma unroll
      for (int j = 0; j < 8; ++j) {
        float f = bu2f((ushortT)vv[j]);
        a += f * f;
      }
    }
    nrm[t] = a;
  }
  __syncthreads();

  {
    const float gam = 0.35355339059327373f;
    const int s0 = w * 16;
    s8 aq0 = *(const s8*)&xq[(s0 + lr) * 72 + q * 8];
    s8 aq1 = *(const s8*)&xq[(s0 + lr) * 72 + 32 + q * 8];
    s8 ak0 = *(const s8*)&xk[(s0 + lr) * 72 + q * 8];
    s8 ak1 = *(const s8*)&xk[(s0 + lr) * 72 + 32 + q * 8];
#pragma unroll
    for (int mt = 0; mt < 4; ++mt) {
      s8 b0 = *(const s8*)&omT[(mt * 16 + lr) * 72 + q * 8];
      s8 b1 = *(const s8*)&omT[(mt * 16 + lr) * 72 + 32 + q * 8];
      f4 cq = (f4){0.f, 0.f, 0.f, 0.f}, ck = (f4){0.f, 0.f, 0.f, 0.f};
      cq = __builtin_amdgcn_mfma_f32_16x16x32_bf16(aq0, b0, cq, 0, 0, 0);
      cq = __builtin_amdgcn_mfma_f32_16x16x32_bf16(aq1, b1, cq, 0, 0, 0);
      ck = __builtin_amdgcn_mfma_f32_16x16x32_bf16(ak0, b0, ck, 0, 0, 0);
      ck = __builtin_amdgcn_mfma_f32_16x16x32_bf16(ak1, b1, ck, 0, 0, 0);
#pragma unroll
      for (int r = 0; r < 4; ++r) {
        const int sr = s0 + q * 4 + r, mc = mt * 16 + lr;
        float vq = expf(gam * cq[r] - 0.0625f * nrm[sr]) * 0.125f;
        float vk = expf(gam * ck[r] - 0.0625f * nrm[64 + sr]) * 0.125f;
        pq[sr * 72 + mc] = f2b(vq);
        ushortT hk = f2b(vk);
        pk[sr * 72 + mc] = hk;
        pkT[mc * 72 + sr] = hk;
      }
    }
  }
  __syncthreads();

  // ================= chunk sums -> global, publish flag =================
  {
    const int d0 = w * 16;
    s8 a0 = *(const s8*)&vT[(d0 + lr) * 72 + q * 8];
    s8 a1 = *(const s8*)&vT[(d0 + lr) * 72 + 32 + q * 8];
    float* outb = KVc + (size_t)(h * NC_ + cc) * DH_ * MF_;
#pragma unroll
    for (int mt = 0; mt < 4; ++mt) {
      s8 b0 = *(const s8*)&pkT[(mt * 16 + lr) * 72 + q * 8];
      s8 b1 = *(const s8*)&pkT[(mt * 16 + lr) * 72 + 32 + q * 8];
      f4 cs = (f4){0.f, 0.f, 0.f, 0.f};
      cs = __builtin_amdgcn_mfma_f32_16x16x32_bf16(a0, b0, cs, 0, 0, 0);
      cs = __builtin_amdgcn_mfma_f32_16x16x32_bf16(a1, b1, cs, 0, 0, 0);
#pragma unroll
      for (int r = 0; r < 4; ++r)
        outb[(size_t)(d0 + q * 4 + r) * MF_ + mt * 16 + lr] = cs[r];
    }
  }
  if (t < 64) {
    float s = 0.f;
#pragma unroll
    for (int seg = 0; seg < 8; ++seg) {
      s8 vv = *(const s8*)&pkT[t * 72 + seg * 8];
#pragma unroll
      for (int j = 0; j < 8; ++j) s += bu2f((ushortT)vv[j]);
    }
    Kc[(size_t)(h * NC_ + cc) * MF_ + t] = s;
  }
  __threadfence();
  __syncthreads();
  if (t == 0)
    __hip_atomic_store(&flags[h * NC_ + cc], 1u, __ATOMIC_RELEASE, __HIP_MEMORY_SCOPE_AGENT);

  // ================= lookback: exclusive prefix over chunks < cc =================
  for (int cp = t; cp < cc; cp += 256)
    while (__hip_atomic_load(&flags[h * NC_ + cp], __ATOMIC_ACQUIRE,
                             __HIP_MEMORY_SCOPE_AGENT) == 0u)
      __builtin_amdgcn_s_sleep(1);
  __syncthreads();
  __threadfence();

  {
    const int s0j = t >> 3, seg0 = t & 7;
    const int s1j = (t + 256) >> 3;
    float a0v[8], a1v[8];
#pragma unroll
    for (int j = 0; j < 8; ++j) { a0v[j] = 0.f; a1v[j] = 0.f; }
    const float* kvbase = KVc + (size_t)(h * NC_) * DH_ * MF_;
    for (int cp = 0; cp < cc; ++cp) {
      const float* kr = kvbase + (size_t)cp * DH_ * MF_;
      f4 x0 = *(const f4*)(kr + s0j * MF_ + seg0 * 8);
      f4 x1 = *(const f4*)(kr + s0j * MF_ + seg0 * 8 + 4);
      f4 y0 = *(const f4*)(kr + s1j * MF_ + seg0 * 8);
      f4 y1 = *(const f4*)(kr + s1j * MF_ + seg0 * 8 + 4);
      a0v[0] += x0.x; a0v[1] += x0.y; a0v[2] += x0.z; a0v[3] += x0.w;
      a0v[4] += x1.x; a0v[5] += x1.y; a0v[6] += x1.z; a0v[7] += x1.w;
      a1v[0] += y0.x; a1v[1] += y0.y; a1v[2] += y0.z; a1v[3] += y0.w;
      a1v[4] += y1.x; a1v[5] += y1.y; a1v[6] += y1.z; a1v[7] += y1.w;
    }
    u32* p0 = (u32*)&kvs[s0j * 72 + seg0 * 8];
    p0[0] = pk2(a0v[0], a0v[1]); p0[1] = pk2(a0v[2], a0v[3]);
    p0[2] = pk2(a0v[4], a0v[5]); p0[3] = pk2(a0v[6], a0v[7]);
    u32* p1 = (u32*)&kvs[s1j * 72 + seg0 * 8];
    p1[0] = pk2(a1v[0], a1v[1]); p1[1] = pk2(a1v[2], a1v[3]);
    p1[2] = pk2(a1v[4], a1v[5]); p1[3] = pk2(a1v[6], a1v[7]);
  }
  if (t < 64) {
    float s = 0.f;
    for (int cp = 0; cp < cc; ++cp) s += Kc[(size_t)(h * NC_ + cp) * MF_ + t];
    kcs[t] = s;
  }
  __syncthreads();

  // ================= phase C: Tm / den / numT =================
  {
    const int s0 = w * 16;
    s8 a0 = *(const s8*)&pq[(s0 + lr) * 72 + q * 8];
    s8 a1 = *(const s8*)&pq[(s0 + lr) * 72 + 32 + q * 8];
#pragma unroll
    for (int tb = 0; tb < 4; ++tb) {
      f4 cs = (f4){0.f, 0.f, 0.f, 0.f};
      if (tb <= w) {
        s8 b0 = *(const s8*)&pk[(tb * 16 + lr) * 72 + q * 8];
        s8 b1 = *(const s8*)&pk[(tb * 16 + lr) * 72 + 32 + q * 8];
        cs = __builtin_amdgcn_mfma_f32_16x16x32_bf16(a0, b0, cs, 0, 0, 0);
        cs = __builtin_amdgcn_mfma_f32_16x16x32_bf16(a1, b1, cs, 0, 0, 0);
      }
#pragma unroll
      for (int r = 0; r < 4; ++r) {
        float v = cs[r];
        if (tb == w && lr > q * 4 + r) v = 0.f;
        tms[(s0 + q * 4 + r) * 72 + tb * 16 + lr] = f2b(v);
      }
    }
  }
  __syncthreads();

  {
    const int s = t >> 2, part = t & 3;
    float dp = 0.f;
    const u32* trow = (const u32*)&tms[s * 72 + part * 16];
#pragma unroll
    for (int j = 0; j < 8; ++j) {
      u32 u = trow[j];
      dp += bu2f((ushortT)(u & 0xffffu)) + bu2f((ushortT)(u >> 16));
    }
    const u32* qrow = (const u32*)&pq[s * 72 + part * 16];
    const f4* kc4 = (const f4*)(kcs + part * 16);
#pragma unroll
    for (int j = 0; j < 4; ++j) {
      f4 b = kc4[j];
      u32 ua = qrow[2 * j], ub = qrow[2 * j + 1];
      dp += bu2f((ushortT)(ua & 0xffffu)) * b.x + bu2f((ushortT)(ua >> 16)) * b.y +
            bu2f((ushortT)(ub & 0xffffu)) * b.z + bu2f((ushortT)(ub >> 16)) * b.w;
    }
    dp += __shfl_down(dp, 2);
    dp += __shfl_down(dp, 1);
    if (part == 0) den[s] = dp + EPS_;
  }
  __syncthreads();

  {
    const int d0 = w * 16;
    const int drow = d0 + lr;
    s8 akv0 = *(const s8*)&kvs[drow * 72 + q * 8];
    s8 akv1 = *(const s8*)&kvs[drow * 72 + 32 + q * 8];
    s8 av0  = *(const s8*)&vT[drow * 72 + q * 8];
    s8 av1  = *(const s8*)&vT[drow * 72 + 32 + q * 8];
#pragma unroll
    for (int sb = 0; sb < 4; ++sb) {
      const int srow = sb * 16 + lr;
      s8 bq0 = *(const s8*)&pq[srow * 72 + q * 8];
      s8 bq1 = *(const s8*)&pq[srow * 72 + 32 + q * 8];
      s8 bt0 = *(const s8*)&tms[srow * 72 + q * 8];
      s8 bt1 = *(const s8*)&tms[srow * 72 + 32 + q * 8];
      f4 cs = (f4){0.f, 0.f, 0.f, 0.f};
      cs = __builtin_amdgcn_mfma_f32_16x16x32_bf16(akv0, bq0, cs, 0, 0, 0);
      cs = __builtin_amdgcn_mfma_f32_16x16x32_bf16(akv1, bq1, cs, 0, 0, 0);
      cs = __builtin_amdgcn_mfma_f32_16x16x32_bf16(av0, bt0, cs, 0, 0, 0);
      cs = __builtin_amdgcn_mfma_f32_16x16x32_bf16(av1, bt1, cs, 0, 0, 0);
      const float inv = 1.f / den[srow];
      u32x2 o;
      o.x = pk2(cs[0] * inv, cs[1] * inv);
      o.y = pk2(cs[2] * inv, cs[3] * inv);
      *(u32x2*)(Aout + (size_t)(cc * CT_ + srow) * DM_ + h * DH_ + d0 + q * 4) = o;
    }
  }
}

// ---------------------------------------------------------------- launch
extern "C" void kernel_launch(void* const* d_in, const int* in_sizes, int n_in,
                              void* d_out, int out_size, void* d_ws, size_t ws_size,
                              hipStream_t stream) {
  const float* x    = (const float*)d_in[0];
  const float* Wq   = (const float*)d_in[1];
  const float* Wk   = (const float*)d_in[2];
  const float* Wv   = (const float*)d_in[3];
  const float* Wo   = (const float*)d_in[4];
  const float* W1   = (const float*)d_in[5];
  const float* W2   = (const float*)d_in[6];
  const float* bq   = (const float*)d_in[7];
  const float* bk   = (const float*)d_in[8];
  const float* bv   = (const float*)d_in[9];
  const float* bo   = (const float*)d_in[10];
  const float* b1   = (const float*)d_in[11];
  const float* b2   = (const float*)d_in[12];
  const float* g1   = (const float*)d_in[13];
  const float* be1  = (const float*)d_in[14];
  const float* g2   = (const float*)d_in[15];
  const float* be2  = (const float*)d_in[16];
  const float* omg  = (const float*)d_in[17];
  float* out = (float*)d_out;

  const size_t MB = 1048576;
  float* f     = (float*)d_ws;
  float* cur   = f;                          // [S,DM] fp32
  float* ln1   = f + 1 * MB;
  float* KVcb  = f + 2 * MB;                 // [H,NC,DH,MF] per-chunk sums
  float* Kcb   = f + 3 * MB;                 // [H,NC,MF]
  u32*   flagb = (u32*)(f + 3 * MB + 16384); // [L][H*NC] lookback flags
  float* PS    = f + 3 * MB + 32768;         // 4 x [S,DM] split-K partials

  ushortT* u    = (ushortT*)(f + 8 * MB);
  ushortT* curb = u;                         // [S,DM] bf16
  ushortT* qbb  = u + 1 * MB;                // attn out bf16
  ushortT* ln1b = u + 2 * MB;
  ushortT* ffb  = u + 3 * MB;                // [S,DFF] bf16 (4M)
  ushortT* wb   = u + 7 * MB;                // transposed weights (2 x LSW_)
  ushortT* omgTb = wb + 2 * LSW_;

  tcast_all<<<10249, 256, 0, stream>>>(x, Wq, Wk, Wv, Wo, W1, W2, omg,
                                       cur, curb, wb, omgTb, flagb);

  const dim3 gFF1(DFF_ / 64, S_ / 64, 1);
  const dim3 gWo(DM_ / 64, S_ / 64, 2);
  const dim3 gW2(DM_ / 64, S_ / 64, 4);
  const dim3 gAttn(NC_, H_);

  for (int l = 0; l < L_; ++l) {
    const ushortT* wl = wb + (size_t)l * LSW_;
    const size_t bo512 = (size_t)l * DM_;
    const size_t boFF = (size_t)l * DFF_;

    attn_mega<<<gAttn, 256, 0, stream>>>(
        curb, wl, bq + bo512, bk + bo512, bv + bo512,
        omgTb + (size_t)l * DH_ * MF_, KVcb, Kcb,
        flagb + (size_t)l * H_ * NC_, qbb);

    mgemm_part<<<gWo, 256, 0, stream>>>(qbb, wl + WOOFF_, PS, DM_, DM_, 256);
    redln<<<S_, 256, 0, stream>>>(PS, 2, bo + bo512, cur, g1 + bo512, be1 + bo512, ln1, ln1b);

    mgemm<true, false, true><<<gFF1, 256, 0, stream>>>(
        ln1b, wl + W1OFF_, b1 + boFF, nullptr, nullptr, ffb, DM_, DFF_);

    mgemm_part<<<gW2, 256, 0, stream>>>(ffb, wl + W2OFF_, PS, DFF_, DM_, 512);
    const bool last = (l == L_ - 1);
    redln<<<S_, 256, 0, stream>>>(PS, 4, b2 + bo512, ln1, g2 + bo512, be2 + bo512,
                                  last ? out : cur, last ? nullptr : curb);
  }
}

// Round 9
// 249.487 us; speedup vs baseline: 1.3958x; 1.3958x over previous
//
#include <hip/hip_runtime.h>
#include <hip/hip_bf16.h>

#define S_  2048
#define DM_ 512
#define H_  8
#define DH_ 64
#define MF_ 64
#define DFF_ 2048
#define L_  2
#define CT_ 64
#define NC_ (S_ / CT_)
#define EPS_ 1e-6f
#define LN_EPS_ 1e-5f

#define LSW_   3145728
#define W1OFF_ 1048576
#define W2OFF_ 2097152
#define WOOFF_ 786432

typedef unsigned short ushortT;
typedef unsigned int u32;
typedef float f4 __attribute__((ext_vector_type(4)));
typedef short s8 __attribute__((ext_vector_type(8)));
typedef u32 u32x2 __attribute__((ext_vector_type(2)));

__device__ __forceinline__ ushortT f2b(float f) {
  union { float f; unsigned u; } v; v.f = f;
  unsigned r = v.u + 0x7fffu + ((v.u >> 16) & 1u);  // RNE
  return (ushortT)(r >> 16);
}
__device__ __forceinline__ float bu2f(ushortT h) {
  union { unsigned u; float f; } v; v.u = ((unsigned)h) << 16; return v.f;
}
__device__ __forceinline__ u32 pk2(float a, float b) {
  return (u32)f2b(a) | ((u32)f2b(b) << 16);
}

// ---------------------------------------------------------------- fused setup
// flat grid: [0,2048) QKVO transpose, [2048,4096) W1, [4096,6144) W2,
// [6144,6152) omega, [6152,10248) copy_in
__global__ __launch_bounds__(256) void tcast_all(
    const float* __restrict__ x,
    const float* __restrict__ Wq, const float* __restrict__ Wk,
    const float* __restrict__ Wv, const float* __restrict__ Wo,
    const float* __restrict__ W1, const float* __restrict__ W2,
    const float* __restrict__ omg,
    float* __restrict__ cur, ushortT* __restrict__ curb,
    ushortT* __restrict__ wb, ushortT* __restrict__ omgTb) {
  const int bid = blockIdx.x;
  const int t = threadIdx.x;
  if (bid >= 6152) {  // copy_in
    const int i = (bid - 6152) * 256 + t;
    float v = x[i];
    cur[i] = v;
    curb[i] = f2b(v);
    return;
  }
  __shared__ ushortT tile[32][33];
  const float* src; ushortT* dst; int K, N, bx, by;
  if (bid < 2048) {
    const int z = bid >> 8, widx = z & 3, lay = z >> 2;
    const float* s4[4] = {Wq, Wk, Wv, Wo};
    src = s4[widx] + (size_t)lay * DM_ * DM_;
    dst = wb + (size_t)lay * LSW_ + (size_t)widx * DM_ * DM_;
    K = DM_; N = DM_; bx = bid & 15; by = (bid >> 4) & 15;
  } else if (bid < 4096) {
    const int r = bid - 2048;
    const int lay = r >> 10;
    src = W1 + (size_t)lay * DM_ * DFF_;
    dst = wb + (size_t)lay * LSW_ + W1OFF_;
    K = DM_; N = DFF_; bx = r & 63; by = (r >> 6) & 15;
  } else if (bid < 6144) {
    const int r = bid - 4096;
    const int lay = r >> 10;
    src = W2 + (size_t)lay * DFF_ * DM_;
    dst = wb + (size_t)lay * LSW_ + W2OFF_;
    K = DFF_; N = DM_; bx = r & 15; by = (r >> 4) & 63;
  } else {
    const int r = bid - 6144;
    const int lay = r >> 2;
    src = omg + (size_t)lay * DH_ * MF_;
    dst = omgTb + (size_t)lay * DH_ * MF_;
    K = DH_; N = MF_; bx = r & 1; by = (r >> 1) & 1;
  }
  const int cc = t & 31, r0 = t >> 5;
  const int n0 = bx * 32, k0 = by * 32;
#pragma unroll
  for (int i = 0; i < 4; ++i) {
    int r = r0 + 8 * i;
    tile[r][cc] = f2b(src[(size_t)(k0 + r) * N + n0 + cc]);
  }
  __syncthreads();
#pragma unroll
  for (int i = 0; i < 4; ++i) {
    int r = r0 + 8 * i;
    dst[(size_t)(n0 + r) * K + k0 + cc] = tile[cc][r];
  }
}

// ---------------------------------------------------------------- MFMA GEMM (full-K, z-slice QKV)
template<bool OUT_BF16>
__global__ __launch_bounds__(256) void mgemm(
    const ushortT* __restrict__ A, const ushortT* __restrict__ Wt,
    const float* __restrict__ bq_, const float* __restrict__ bk_,
    const float* __restrict__ bv_,
    float* __restrict__ Cf, ushortT* __restrict__ Cb, int K, int N) {
  __shared__ ushortT sA[2][2048];
  __shared__ ushortT sB[2][2048];
  const int t = threadIdx.x;
  const int w = t >> 6, l = t & 63;
  const int wm = w >> 1, wn = w & 1;
  const int n0 = blockIdx.x * 64, m0 = blockIdx.y * 64;
  const int z = blockIdx.z;
  const ushortT* Wz = Wt + (size_t)z * K * N;
  const float* bias = (z == 0) ? bq_ : (z == 1 ? bk_ : bv_);

  const int rs = w * 16 + (l >> 2);
  const int qs = (l & 3) ^ ((rs >> 1) & 3);
  const ushortT* gA = A  + (size_t)(m0 + rs) * K + qs * 8;
  const ushortT* gB = Wz + (size_t)(n0 + rs) * K + qs * 8;

  const int Ra = wm * 32 + (l & 15);
  const int Rb = wn * 32 + (l & 15);
  const int qq = l >> 4;
  const int aoff = (Ra * 4 + (qq ^ ((Ra >> 1) & 3))) * 8;
  const int boff = (Rb * 4 + (qq ^ ((Rb >> 1) & 3))) * 8;

  f4 acc[2][2];
#pragma unroll
  for (int i = 0; i < 2; ++i)
#pragma unroll
    for (int j = 0; j < 2; ++j) acc[i][j] = (f4){0.f, 0.f, 0.f, 0.f};

  auto stage = [&](int buf, int ko) {
    __builtin_amdgcn_global_load_lds(
        (const __attribute__((address_space(1))) void*)(gA + ko),
        (__attribute__((address_space(3))) void*)(&sA[buf][w * 512]), 16, 0, 0);
    __builtin_amdgcn_global_load_lds(
        (const __attribute__((address_space(1))) void*)(gB + ko),
        (__attribute__((address_space(3))) void*)(&sB[buf][w * 512]), 16, 0, 0);
  };

  stage(0, 0);
  const int nk = K >> 5;
  for (int ks = 0; ks < nk; ++ks) {
    __syncthreads();
    if (ks + 1 < nk) stage((ks + 1) & 1, (ks + 1) * 32);
    const ushortT* pa = sA[ks & 1];
    const ushortT* pb = sB[ks & 1];
    s8 a0 = *(const s8*)(pa + aoff);
    s8 a1 = *(const s8*)(pa + aoff + 512);
    s8 b0 = *(const s8*)(pb + boff);
    s8 b1 = *(const s8*)(pb + boff + 512);
    acc[0][0] = __builtin_amdgcn_mfma_f32_16x16x32_bf16(a0, b0, acc[0][0], 0, 0, 0);
    acc[0][1] = __builtin_amdgcn_mfma_f32_16x16x32_bf16(a0, b1, acc[0][1], 0, 0, 0);
    acc[1][0] = __builtin_amdgcn_mfma_f32_16x16x32_bf16(a1, b0, acc[1][0], 0, 0, 0);
    acc[1][1] = __builtin_amdgcn_mfma_f32_16x16x32_bf16(a1, b1, acc[1][1], 0, 0, 0);
  }

  const size_t outz = (size_t)z * S_ * N;
  const int colb = n0 + wn * 32 + (l & 15);
  const int rowb = m0 + wm * 32 + ((l >> 4) << 2);
#pragma unroll
  for (int mt = 0; mt < 2; ++mt) {
#pragma unroll
    for (int nt = 0; nt < 2; ++nt) {
      const int c = colb + nt * 16;
      const float bv = bias[c];
#pragma unroll
      for (int r = 0; r < 4; ++r) {
        const int rr = rowb + mt * 16 + r;
        float v = acc[mt][nt][r] + bv;
        if (OUT_BF16) Cb[outz + (size_t)rr * N + c] = f2b(v);
        else          Cf[outz + (size_t)rr * N + c] = v;
      }
    }
  }
}

// ---------------------------------------------------------------- MFMA GEMM partial 64-tile (split-K)
__global__ __launch_bounds__(256) void mgemm_part(
    const ushortT* __restrict__ A, const ushortT* __restrict__ Wt,
    float* __restrict__ PS, int K, int N, int KS) {
  __shared__ ushortT sA[2][2048];
  __shared__ ushortT sB[2][2048];
  const int t = threadIdx.x;
  const int w = t >> 6, l = t & 63;
  const int wm = w >> 1, wn = w & 1;
  const int n0 = blockIdx.x * 64, m0 = blockIdx.y * 64;
  const int z = blockIdx.z;

  const int rs = w * 16 + (l >> 2);
  const int qs = (l & 3) ^ ((rs >> 1) & 3);
  const ushortT* gA = A  + (size_t)(m0 + rs) * K + z * KS + qs * 8;
  const ushortT* gB = Wt + (size_t)(n0 + rs) * K + z * KS + qs * 8;

  const int Ra = wm * 32 + (l & 15);
  const int Rb = wn * 32 + (l & 15);
  const int qq = l >> 4;
  const int aoff = (Ra * 4 + (qq ^ ((Ra >> 1) & 3))) * 8;
  const int boff = (Rb * 4 + (qq ^ ((Rb >> 1) & 3))) * 8;

  f4 acc[2][2];
#pragma unroll
  for (int i = 0; i < 2; ++i)
#pragma unroll
    for (int j = 0; j < 2; ++j) acc[i][j] = (f4){0.f, 0.f, 0.f, 0.f};

  auto stage = [&](int buf, int ko) {
    __builtin_amdgcn_global_load_lds(
        (const __attribute__((address_space(1))) void*)(gA + ko),
        (__attribute__((address_space(3))) void*)(&sA[buf][w * 512]), 16, 0, 0);
    __builtin_amdgcn_global_load_lds(
        (const __attribute__((address_space(1))) void*)(gB + ko),
        (__attribute__((address_space(3))) void*)(&sB[buf][w * 512]), 16, 0, 0);
  };

  stage(0, 0);
  const int nk = KS >> 5;
  for (int ks = 0; ks < nk; ++ks) {
    __syncthreads();
    if (ks + 1 < nk) stage((ks + 1) & 1, (ks + 1) * 32);
    const ushortT* pa = sA[ks & 1];
    const ushortT* pb = sB[ks & 1];
    s8 a0 = *(const s8*)(pa + aoff);
    s8 a1 = *(const s8*)(pa + aoff + 512);
    s8 b0 = *(const s8*)(pb + boff);
    s8 b1 = *(const s8*)(pb + boff + 512);
    acc[0][0] = __builtin_amdgcn_mfma_f32_16x16x32_bf16(a0, b0, acc[0][0], 0, 0, 0);
    acc[0][1] = __builtin_amdgcn_mfma_f32_16x16x32_bf16(a0, b1, acc[0][1], 0, 0, 0);
    acc[1][0] = __builtin_amdgcn_mfma_f32_16x16x32_bf16(a1, b0, acc[1][0], 0, 0, 0);
    acc[1][1] = __builtin_amdgcn_mfma_f32_16x16x32_bf16(a1, b1, acc[1][1], 0, 0, 0);
  }

  float* out = PS + (size_t)z * S_ * N;
  const int colb = n0 + wn * 32 + (l & 15);
  const int rowb = m0 + wm * 32 + ((l >> 4) << 2);
#pragma unroll
  for (int mt = 0; mt < 2; ++mt) {
#pragma unroll
    for (int nt = 0; nt < 2; ++nt) {
      const int c = colb + nt * 16;
#pragma unroll
      for (int r = 0; r < 4; ++r)
        out[(size_t)(rowb + mt * 16 + r) * N + c] = acc[mt][nt][r];
    }
  }
}

// ---------------------------------------------------------------- MFMA GEMM, 128x128 tile (m97-style)
// FULL=true : out = bf16 relu(A@Wt^T + bias)  (W1)
// FULL=false: out = fp32 partial A[:,zKS:]@Wt[:,zKS:]^T to PS slice z  (W2 split-K)
template<bool FULL>
__global__ __launch_bounds__(256) void mgemm128(
    const ushortT* __restrict__ A, const ushortT* __restrict__ Wt,
    const float* __restrict__ bias, float* __restrict__ PS,
    ushortT* __restrict__ Cb, int K, int N, int KS) {
  __shared__ ushortT sA[2][4096];
  __shared__ ushortT sB[2][4096];
  const int t = threadIdx.x;
  const int w = t >> 6, l = t & 63, lr = l & 15, q = l >> 4;
  const int wm = w >> 1, wn = w & 1;
  const int n0 = blockIdx.x * 128, m0 = blockIdx.y * 128;
  const int z = blockIdx.z;

  // staging: 512 granule-slots/matrix; wave w covers slots [w*128, w*128+128) via 2 calls
  const int s0 = w * 128 + l, s1 = s0 + 64;
  const int r0 = s0 >> 2, kq0 = (s0 & 3) ^ ((r0 >> 1) & 3);
  const int r1 = s1 >> 2, kq1 = (s1 & 3) ^ ((r1 >> 1) & 3);
  const ushortT* gA0 = A  + (size_t)(m0 + r0) * K + z * KS + kq0 * 8;
  const ushortT* gA1 = A  + (size_t)(m0 + r1) * K + z * KS + kq1 * 8;
  const ushortT* gB0 = Wt + (size_t)(n0 + r0) * K + z * KS + kq0 * 8;
  const ushortT* gB1 = Wt + (size_t)(n0 + r1) * K + z * KS + kq1 * 8;

  // fragment read offsets: 4 m-tiles / 4 n-tiles per wave
  int aoff[4], boff[4];
#pragma unroll
  for (int i = 0; i < 4; ++i) {
    const int RA = wm * 64 + i * 16 + lr;
    const int RB = wn * 64 + i * 16 + lr;
    aoff[i] = (RA * 4 + (q ^ ((RA >> 1) & 3))) * 8;
    boff[i] = (RB * 4 + (q ^ ((RB >> 1) & 3))) * 8;
  }

  f4 acc[4][4];
#pragma unroll
  for (int i = 0; i < 4; ++i)
#pragma unroll
    for (int j = 0; j < 4; ++j) acc[i][j] = (f4){0.f, 0.f, 0.f, 0.f};

  auto stage = [&](int buf, int ko) {
    __builtin_amdgcn_global_load_lds(
        (const __attribute__((address_space(1))) void*)(gA0 + ko),
        (__attribute__((address_space(3))) void*)(&sA[buf][w * 1024]), 16, 0, 0);
    __builtin_amdgcn_global_load_lds(
        (const __attribute__((address_space(1))) void*)(gA1 + ko),
        (__attribute__((address_space(3))) void*)(&sA[buf][w * 1024 + 512]), 16, 0, 0);
    __builtin_amdgcn_global_load_lds(
        (const __attribute__((address_space(1))) void*)(gB0 + ko),
        (__attribute__((address_space(3))) void*)(&sB[buf][w * 1024]), 16, 0, 0);
    __builtin_amdgcn_global_load_lds(
        (const __attribute__((address_space(1))) void*)(gB1 + ko),
        (__attribute__((address_space(3))) void*)(&sB[buf][w * 1024 + 512]), 16, 0, 0);
  };

  stage(0, 0);
  const int nk = (FULL ? K : KS) >> 5;
  for (int ks = 0; ks < nk; ++ks) {
    __syncthreads();
    if (ks + 1 < nk) stage((ks + 1) & 1, (ks + 1) * 32);
    const ushortT* pa = sA[ks & 1];
    const ushortT* pb = sB[ks & 1];
    s8 a[4], b[4];
#pragma unroll
    for (int i = 0; i < 4; ++i) {
      a[i] = *(const s8*)(pa + aoff[i]);
      b[i] = *(const s8*)(pb + boff[i]);
    }
#pragma unroll
    for (int mt = 0; mt < 4; ++mt)
#pragma unroll
      for (int nt = 0; nt < 4; ++nt)
        acc[mt][nt] = __builtin_amdgcn_mfma_f32_16x16x32_bf16(a[mt], b[nt], acc[mt][nt], 0, 0, 0);
  }

  const int colb = n0 + wn * 64 + lr;
  const int rowb = m0 + wm * 64 + q * 4;
  if (FULL) {
#pragma unroll
    for (int nt = 0; nt < 4; ++nt) {
      const int c = colb + nt * 16;
      const float bv = bias[c];
#pragma unroll
      for (int mt = 0; mt < 4; ++mt) {
#pragma unroll
        for (int r = 0; r < 4; ++r) {
          const int rr = rowb + mt * 16 + r;
          Cb[(size_t)rr * N + c] = f2b(fmaxf(acc[mt][nt][r] + bv, 0.f));
        }
      }
    }
  } else {
    float* out = PS + (size_t)z * S_ * N;
#pragma unroll
    for (int mt = 0; mt < 4; ++mt)
#pragma unroll
      for (int nt = 0; nt < 4; ++nt) {
        const int c = colb + nt * 16;
#pragma unroll
        for (int r = 0; r < 4; ++r)
          out[(size_t)(rowb + mt * 16 + r) * N + c] = acc[mt][nt][r];
      }
  }
}

// ---------------------------------------------------------------- reduce splits + bias + res + LN
__global__ __launch_bounds__(256) void redln(const float* __restrict__ PS, int nsplit,
                                             const float* __restrict__ bias,
                                             const float* __restrict__ res,
                                             const float* __restrict__ g,
                                             const float* __restrict__ be,
                                             float* __restrict__ outF,
                                             ushortT* __restrict__ outB) {
  const int s = blockIdx.x, t = threadIdx.x;
  float v0 = bias[t] + res[(size_t)s * DM_ + t];
  float v1 = bias[t + 256] + res[(size_t)s * DM_ + 256 + t];
  for (int z = 0; z < nsplit; ++z) {
    const float* p = PS + (size_t)z * S_ * DM_ + (size_t)s * DM_;
    v0 += p[t];
    v1 += p[256 + t];
  }
  float sum = v0 + v1, sq = v0 * v0 + v1 * v1;
  for (int off = 32; off > 0; off >>= 1) {
    sum += __shfl_down(sum, off);
    sq += __shfl_down(sq, off);
  }
  __shared__ float ssum[4], ssq[4];
  __shared__ float smean, srstd;
  const int w = t >> 6;
  if ((t & 63) == 0) { ssum[w] = sum; ssq[w] = sq; }
  __syncthreads();
  if (t == 0) {
    float S1 = ssum[0] + ssum[1] + ssum[2] + ssum[3];
    float S2 = ssq[0] + ssq[1] + ssq[2] + ssq[3];
    float mu = S1 / DM_;
    smean = mu;
    srstd = rsqrtf(S2 / DM_ - mu * mu + LN_EPS_);
  }
  __syncthreads();
  const float mu = smean, rs = srstd;
  float o0 = (v0 - mu) * rs * g[t] + be[t];
  float o1 = (v1 - mu) * rs * g[256 + t] + be[256 + t];
  outF[(size_t)s * DM_ + t] = o0;
  outF[(size_t)s * DM_ + 256 + t] = o1;
  if (outB) {
    outB[(size_t)s * DM_ + t] = f2b(o0);
    outB[(size_t)s * DM_ + 256 + t] = f2b(o1);
  }
}

// ---------------------------------------------------------------- FAVOR+ + chunk sums (fused, MFMA)
__global__ __launch_bounds__(256) void favor_cs(const ushortT* __restrict__ qkv,
                                                const ushortT* __restrict__ omgT,
                                                ushortT* __restrict__ PQb,
                                                ushortT* __restrict__ PKb,
                                                float* __restrict__ KVcT,
                                                float* __restrict__ Kc) {
  const int c = blockIdx.x, h = blockIdx.y, t = threadIdx.x;
  const int w = t >> 6, l = t & 63, lr = l & 15, q = l >> 4;
  __shared__ ushortT xq[64 * 72], xk[64 * 72], vT[64 * 72], omT[64 * 72];
  __shared__ ushortT pq[64 * 72], pk[64 * 72], pkT[64 * 72];
  __shared__ float nrm[128];

  const ushortT* qg = qkv + (size_t)(c * CT_) * DM_ + h * DH_;
  const ushortT* kg = qg + (size_t)S_ * DM_;
  const ushortT* vg = kg + (size_t)S_ * DM_;

  for (int i = t; i < 512; i += 256) {
    const int s = i >> 3, seg = i & 7;
    *(s8*)&xq[s * 72 + seg * 8] = *(const s8*)(qg + (size_t)s * DM_ + seg * 8);
    *(s8*)&xk[s * 72 + seg * 8] = *(const s8*)(kg + (size_t)s * DM_ + seg * 8);
    s8 av = *(const s8*)(vg + (size_t)s * DM_ + seg * 8);
#pragma unroll
    for (int j = 0; j < 8; ++j) vT[(seg * 8 + j) * 72 + s] = (ushortT)av[j];
    *(s8*)&omT[s * 72 + seg * 8] = *(const s8*)(omgT + s * 64 + seg * 8);
  }
  __syncthreads();

  if (t < 128) {
    const ushortT* src = (t < 64) ? xq : xk;
    const int s = t & 63;
    float a = 0.f;
#pragma unroll
    for (int seg = 0; seg < 8; ++seg) {
      s8 vv = *(const s8*)(src + s * 72 + seg * 8);
#pragma unroll
      for (int j = 0; j < 8; ++j) {
        float f = bu2f((ushortT)vv[j]);
        a += f * f;
      }
    }
    nrm[t] = a;
  }
  __syncthreads();

  {
    const float gam = 0.35355339059327373f;
    const int s0 = w * 16;
    s8 aq0 = *(const s8*)&xq[(s0 + lr) * 72 + q * 8];
    s8 aq1 = *(const s8*)&xq[(s0 + lr) * 72 + 32 + q * 8];
    s8 ak0 = *(const s8*)&xk[(s0 + lr) * 72 + q * 8];
    s8 ak1 = *(const s8*)&xk[(s0 + lr) * 72 + 32 + q * 8];
#pragma unroll
    for (int mt = 0; mt < 4; ++mt) {
      s8 b0 = *(const s8*)&omT[(mt * 16 + lr) * 72 + q * 8];
      s8 b1 = *(const s8*)&omT[(mt * 16 + lr) * 72 + 32 + q * 8];
      f4 cq = (f4){0.f, 0.f, 0.f, 0.f}, ck = (f4){0.f, 0.f, 0.f, 0.f};
      cq = __builtin_amdgcn_mfma_f32_16x16x32_bf16(aq0, b0, cq, 0, 0, 0);
      cq = __builtin_amdgcn_mfma_f32_16x16x32_bf16(aq1, b1, cq, 0, 0, 0);
      ck = __builtin_amdgcn_mfma_f32_16x16x32_bf16(ak0, b0, ck, 0, 0, 0);
      ck = __builtin_amdgcn_mfma_f32_16x16x32_bf16(ak1, b1, ck, 0, 0, 0);
#pragma unroll
      for (int r = 0; r < 4; ++r) {
        const int sr = s0 + q * 4 + r, mc = mt * 16 + lr;
        float vq = expf(gam * cq[r] - 0.0625f * nrm[sr]) * 0.125f;
        float vk = expf(gam * ck[r] - 0.0625f * nrm[64 + sr]) * 0.125f;
        pq[sr * 72 + mc] = f2b(vq);
        ushortT hk = f2b(vk);
        pk[sr * 72 + mc] = hk;
        pkT[mc * 72 + sr] = hk;
      }
    }
  }
  __syncthreads();

  {
    const int d0 = w * 16;
    s8 a0 = *(const s8*)&vT[(d0 + lr) * 72 + q * 8];
    s8 a1 = *(const s8*)&vT[(d0 + lr) * 72 + 32 + q * 8];
    float* outb = KVcT + (size_t)(h * NC_ + c) * DH_ * MF_;
#pragma unroll
    for (int mt = 0; mt < 4; ++mt) {
      s8 b0 = *(const s8*)&pkT[(mt * 16 + lr) * 72 + q * 8];
      s8 b1 = *(const s8*)&pkT[(mt * 16 + lr) * 72 + 32 + q * 8];
      f4 cc = (f4){0.f, 0.f, 0.f, 0.f};
      cc = __builtin_amdgcn_mfma_f32_16x16x32_bf16(a0, b0, cc, 0, 0, 0);
      cc = __builtin_amdgcn_mfma_f32_16x16x32_bf16(a1, b1, cc, 0, 0, 0);
#pragma unroll
      for (int r = 0; r < 4; ++r)
        outb[(size_t)(d0 + q * 4 + r) * MF_ + mt * 16 + lr] = cc[r];
    }
  }
  if (t < 64) {
    float s = 0.f;
#pragma unroll
    for (int seg = 0; seg < 8; ++seg) {
      s8 vv = *(const s8*)&pkT[t * 72 + seg * 8];
#pragma unroll
      for (int j = 0; j < 8; ++j) s += bu2f((ushortT)vv[j]);
    }
    Kc[(size_t)(h * NC_ + c) * MF_ + t] = s;
  }
  for (int i = t; i < 512; i += 256) {
    const int s = i >> 3, seg = i & 7;
    *(s8*)(PQb + (size_t)(c * CT_ + s) * DM_ + h * MF_ + seg * 8) = *(const s8*)&pq[s * 72 + seg * 8];
    *(s8*)(PKb + (size_t)(c * CT_ + s) * DM_ + h * MF_ + seg * 8) = *(const s8*)&pk[s * 72 + seg * 8];
  }
}

// ---------------------------------------------------------------- prefix scan (register-resident)
__global__ __launch_bounds__(256) void prefix2(float* __restrict__ KVc,
                                               float* __restrict__ Kc) {
  const int h = blockIdx.x, seg = blockIdx.y, t = threadIdx.x;
  if (seg < 16) {
    float* base = KVc + (size_t)h * NC_ * MF_ * DH_ + seg * 256 + t;
    float v[NC_];
#pragma unroll
    for (int c = 0; c < NC_; ++c) v[c] = base[(size_t)c * MF_ * DH_];
    float run = 0.f;
#pragma unroll
    for (int c = 0; c < NC_; ++c) {
      float tmp = v[c];
      base[(size_t)c * MF_ * DH_] = run;
      run += tmp;
    }
  } else if (t < MF_) {
    float* base = Kc + (size_t)h * NC_ * MF_ + t;
    float v[NC_];
#pragma unroll
    for (int c = 0; c < NC_; ++c) v[c] = base[(size_t)c * MF_];
    float run = 0.f;
#pragma unroll
    for (int c = 0; c < NC_; ++c) {
      float tmp = v[c];
      base[(size_t)c * MF_] = run;
      run += tmp;
    }
  }
}

// ---------------------------------------------------------------- attention out (MFMA, bf16 in)
__global__ __launch_bounds__(256) void attn_mfma(const ushortT* __restrict__ PQ,
                                                 const ushortT* __restrict__ PK,
                                                 const ushortT* __restrict__ V,
                                                 const float* __restrict__ KVcT,
                                                 const float* __restrict__ Kc,
                                                 ushortT* __restrict__ Aout) {
  const int cc = blockIdx.x, h = blockIdx.y, t = threadIdx.x;
  const int w = t >> 6, l = t & 63;
  const int lr = l & 15, q = l >> 4;

  __shared__ ushortT pqs[64 * 72];
  __shared__ ushortT pks[64 * 72];
  __shared__ ushortT vts[64 * 72];
  __shared__ ushortT kvs[64 * 72];
  __shared__ ushortT tms[64 * 72];
  __shared__ float dpart[256];
  __shared__ float den[64];

  for (int i = t; i < 512; i += 256) {
    const int s = i >> 3, seg = i & 7;
    *(s8*)&pqs[s * 72 + seg * 8] = *(const s8*)(PQ + (size_t)(cc * CT_ + s) * DM_ + h * MF_ + seg * 8);
    *(s8*)&pks[s * 72 + seg * 8] = *(const s8*)(PK + (size_t)(cc * CT_ + s) * DM_ + h * MF_ + seg * 8);
    s8 av = *(const s8*)(V + (size_t)(cc * CT_ + s) * DM_ + h * DH_ + seg * 8);
#pragma unroll
    for (int j = 0; j < 8; ++j) vts[(seg * 8 + j) * 72 + s] = (ushortT)av[j];
    const float* kr = KVcT + (size_t)((h * NC_ + cc) * DH_ + s) * MF_ + seg * 8;
    f4 g0 = *(const f4*)kr;
    f4 g1 = *(const f4*)(kr + 4);
    u32* p = (u32*)&kvs[s * 72 + seg * 8];
    p[0] = pk2(g0.x, g0.y); p[1] = pk2(g0.z, g0.w);
    p[2] = pk2(g1.x, g1.y); p[3] = pk2(g1.z, g1.w);
  }
  __syncthreads();

  {
    const int s0 = w * 16;
    s8 a0 = *(const s8*)&pqs[(s0 + lr) * 72 + q * 8];
    s8 a1 = *(const s8*)&pqs[(s0 + lr) * 72 + 32 + q * 8];
#pragma unroll
    for (int tb = 0; tb < 4; ++tb) {
      f4 c = (f4){0.f, 0.f, 0.f, 0.f};
      if (tb <= w) {
        s8 b0 = *(const s8*)&pks[(tb * 16 + lr) * 72 + q * 8];
        s8 b1 = *(const s8*)&pks[(tb * 16 + lr) * 72 + 32 + q * 8];
        c = __builtin_amdgcn_mfma_f32_16x16x32_bf16(a0, b0, c, 0, 0, 0);
        c = __builtin_amdgcn_mfma_f32_16x16x32_bf16(a1, b1, c, 0, 0, 0);
      }
#pragma unroll
      for (int r = 0; r < 4; ++r) {
        float v = c[r];
        if (tb == w && lr > q * 4 + r) v = 0.f;
        tms[(s0 + q * 4 + r) * 72 + tb * 16 + lr] = f2b(v);
      }
    }
  }
  __syncthreads();

  {
    const int s = t >> 2, part = t & 3;
    float dp = 0.f;
    const u32* trow = (const u32*)&tms[s * 72 + part * 16];
#pragma unroll
    for (int j = 0; j < 8; ++j) {
      u32 u = trow[j];
      dp += bu2f((ushortT)(u & 0xffffu)) + bu2f((ushortT)(u >> 16));
    }
    const u32* qrow = (const u32*)&pqs[s * 72 + part * 16];
    const f4* kc4 = (const f4*)(Kc + (size_t)(h * NC_ + cc) * MF_ + part * 16);
#pragma unroll
    for (int j = 0; j < 4; ++j) {
      f4 b = kc4[j];
      u32 ua = qrow[2 * j], ub = qrow[2 * j + 1];
      dp += bu2f((ushortT)(ua & 0xffffu)) * b.x + bu2f((ushortT)(ua >> 16)) * b.y +
            bu2f((ushortT)(ub & 0xffffu)) * b.z + bu2f((ushortT)(ub >> 16)) * b.w;
    }
    dpart[t] = dp;
  }
  __syncthreads();
  if (t < 64)
    den[t] = dpart[4 * t] + dpart[4 * t + 1] + dpart[4 * t + 2] + dpart[4 * t + 3] + EPS_;
  __syncthreads();

  {
    const int d0 = w * 16;
    const int drow = d0 + lr;
    s8 akv0 = *(const s8*)&kvs[drow * 72 + q * 8];
    s8 akv1 = *(const s8*)&kvs[drow * 72 + 32 + q * 8];
    s8 av0  = *(const s8*)&vts[drow * 72 + q * 8];
    s8 av1  = *(const s8*)&vts[drow * 72 + 32 + q * 8];
#pragma unroll
    for (int sb = 0; sb < 4; ++sb) {
      const int srow = sb * 16 + lr;
      s8 bq0 = *(const s8*)&pqs[srow * 72 + q * 8];
      s8 bq1 = *(const s8*)&pqs[srow * 72 + 32 + q * 8];
      s8 bt0 = *(const s8*)&tms[srow * 72 + q * 8];
      s8 bt1 = *(const s8*)&tms[srow * 72 + 32 + q * 8];
      f4 c = (f4){0.f, 0.f, 0.f, 0.f};
      c = __builtin_amdgcn_mfma_f32_16x16x32_bf16(akv0, bq0, c, 0, 0, 0);
      c = __builtin_amdgcn_mfma_f32_16x16x32_bf16(akv1, bq1, c, 0, 0, 0);
      c = __builtin_amdgcn_mfma_f32_16x16x32_bf16(av0, bt0, c, 0, 0, 0);
      c = __builtin_amdgcn_mfma_f32_16x16x32_bf16(av1, bt1, c, 0, 0, 0);
      const float inv = 1.f / den[srow];
      u32x2 o;
      o.x = pk2(c[0] * inv, c[1] * inv);
      o.y = pk2(c[2] * inv, c[3] * inv);
      *(u32x2*)(Aout + (size_t)(cc * CT_ + srow) * DM_ + h * DH_ + d0 + q * 4) = o;
    }
  }
}

// ---------------------------------------------------------------- launch
extern "C" void kernel_launch(void* const* d_in, const int* in_sizes, int n_in,
                              void* d_out, int out_size, void* d_ws, size_t ws_size,
                              hipStream_t stream) {
  const float* x    = (const float*)d_in[0];
  const float* Wq   = (const float*)d_in[1];
  const float* Wk   = (const float*)d_in[2];
  const float* Wv   = (const float*)d_in[3];
  const float* Wo   = (const float*)d_in[4];
  const float* W1   = (const float*)d_in[5];
  const float* W2   = (const float*)d_in[6];
  const float* bq   = (const float*)d_in[7];
  const float* bk   = (const float*)d_in[8];
  const float* bv   = (const float*)d_in[9];
  const float* bo   = (const float*)d_in[10];
  const float* b1   = (const float*)d_in[11];
  const float* b2   = (const float*)d_in[12];
  const float* g1   = (const float*)d_in[13];
  const float* be1  = (const float*)d_in[14];
  const float* g2   = (const float*)d_in[15];
  const float* be2  = (const float*)d_in[16];
  const float* omg  = (const float*)d_in[17];
  float* out = (float*)d_out;

  const size_t MB = 1048576;
  float* f    = (float*)d_ws;
  float* cur  = f;                 // [S,DM] fp32
  float* ln1  = f + 1 * MB;
  float* KVcb = f + 2 * MB;        // [H,NC,DH,MF]
  float* Kcb  = f + 3 * MB;
  float* PS   = f + 3 * MB + 16384;  // 4 x [S,DM] fp32

  ushortT* u    = (ushortT*)(f + 8 * MB);
  ushortT* curb = u;
  ushortT* qkb  = u + 1 * MB;      // [3][S,DM] q,k,v bf16
  ushortT* pqb  = u + 4 * MB;
  ushortT* pkb  = u + 5 * MB;
  ushortT* qbb  = u + 6 * MB;      // attn out bf16
  ushortT* ln1b = u + 7 * MB;
  ushortT* ffb  = u + 8 * MB;      // [S,DFF] bf16 (4M)
  ushortT* wb   = u + 12 * MB;     // transposed weights (2 x LSW_)
  ushortT* omgTb = wb + 2 * LSW_;

  tcast_all<<<10248, 256, 0, stream>>>(x, Wq, Wk, Wv, Wo, W1, W2, omg,
                                       cur, curb, wb, omgTb);

  const dim3 gQKV(DM_ / 64, S_ / 64, 3);
  const dim3 gWo(DM_ / 64, S_ / 64, 2);
  const dim3 gW1(DFF_ / 128, S_ / 128, 1);   // (16,16)
  const dim3 gW2(DM_ / 128, S_ / 128, 4);    // (4,16,4)
  const dim3 gAttn(NC_, H_);
  const dim3 gPre(H_, 17);

  for (int l = 0; l < L_; ++l) {
    const ushortT* wl = wb + (size_t)l * LSW_;
    const size_t bo512 = (size_t)l * DM_;
    const size_t boFF = (size_t)l * DFF_;

    mgemm<true><<<gQKV, 256, 0, stream>>>(
        curb, wl, bq + bo512, bk + bo512, bv + bo512, nullptr, qkb, DM_, DM_);

    favor_cs<<<gAttn, 256, 0, stream>>>(qkb, omgTb + (size_t)l * DH_ * MF_,
                                        pqb, pkb, KVcb, Kcb);
    prefix2<<<gPre, 256, 0, stream>>>(KVcb, Kcb);
    attn_mfma<<<gAttn, 256, 0, stream>>>(pqb, pkb, qkb + 2 * (size_t)S_ * DM_,
                                         KVcb, Kcb, qbb);

    mgemm_part<<<gWo, 256, 0, stream>>>(qbb, wl + WOOFF_, PS, DM_, DM_, 256);
    redln<<<S_, 256, 0, stream>>>(PS, 2, bo + bo512, cur, g1 + bo512, be1 + bo512, ln1, ln1b);

    mgemm128<true><<<gW1, 256, 0, stream>>>(
        ln1b, wl + W1OFF_, b1 + boFF, nullptr, ffb, DM_, DFF_, 0);

    mgemm128<false><<<gW2, 256, 0, stream>>>(
        ffb, wl + W2OFF_, nullptr, PS, nullptr, DFF_, DM_, 512);
    const bool last = (l == L_ - 1);
    redln<<<S_, 256, 0, stream>>>(PS, 4, b2 + bo512, ln1, g2 + bo512, be2 + bo512,
                                  last ? out : cur, last ? nullptr : curb);
  }
}

// Round 10
// 244.641 us; speedup vs baseline: 1.4234x; 1.0198x over previous
//
#include <hip/hip_runtime.h>
#include <hip/hip_bf16.h>

#define S_  2048
#define DM_ 512
#define H_  8
#define DH_ 64
#define MF_ 64
#define DFF_ 2048
#define L_  2
#define CT_ 64
#define NC_ (S_ / CT_)
#define EPS_ 1e-6f
#define LN_EPS_ 1e-5f

#define LSW_   3145728
#define W1OFF_ 1048576
#define W2OFF_ 2097152
#define WOOFF_ 786432

typedef unsigned short ushortT;
typedef unsigned int u32;
typedef float f4 __attribute__((ext_vector_type(4)));
typedef short s8 __attribute__((ext_vector_type(8)));
typedef u32 u32x2 __attribute__((ext_vector_type(2)));
typedef ushortT us4 __attribute__((ext_vector_type(4)));

__device__ __forceinline__ ushortT f2b(float f) {
  union { float f; unsigned u; } v; v.f = f;
  unsigned r = v.u + 0x7fffu + ((v.u >> 16) & 1u);  // RNE
  return (ushortT)(r >> 16);
}
__device__ __forceinline__ float bu2f(ushortT h) {
  union { unsigned u; float f; } v; v.u = ((unsigned)h) << 16; return v.f;
}
__device__ __forceinline__ u32 pk2(float a, float b) {
  return (u32)f2b(a) | ((u32)f2b(b) << 16);
}

// ---------------------------------------------------------------- fused setup
// flat grid: [0,2048) QKVO transpose, [2048,4096) W1, [4096,6144) W2,
// [6144,6152) omega, [6152,10248) copy_in
__global__ __launch_bounds__(256) void tcast_all(
    const float* __restrict__ x,
    const float* __restrict__ Wq, const float* __restrict__ Wk,
    const float* __restrict__ Wv, const float* __restrict__ Wo,
    const float* __restrict__ W1, const float* __restrict__ W2,
    const float* __restrict__ omg,
    float* __restrict__ cur, ushortT* __restrict__ curb,
    ushortT* __restrict__ wb, ushortT* __restrict__ omgTb) {
  const int bid = blockIdx.x;
  const int t = threadIdx.x;
  if (bid >= 6152) {  // copy_in
    const int i = (bid - 6152) * 256 + t;
    float v = x[i];
    cur[i] = v;
    curb[i] = f2b(v);
    return;
  }
  __shared__ ushortT tile[32][33];
  const float* src; ushortT* dst; int K, N, bx, by;
  if (bid < 2048) {
    const int z = bid >> 8, widx = z & 3, lay = z >> 2;
    const float* s4[4] = {Wq, Wk, Wv, Wo};
    src = s4[widx] + (size_t)lay * DM_ * DM_;
    dst = wb + (size_t)lay * LSW_ + (size_t)widx * DM_ * DM_;
    K = DM_; N = DM_; bx = bid & 15; by = (bid >> 4) & 15;
  } else if (bid < 4096) {
    const int r = bid - 2048;
    const int lay = r >> 10;
    src = W1 + (size_t)lay * DM_ * DFF_;
    dst = wb + (size_t)lay * LSW_ + W1OFF_;
    K = DM_; N = DFF_; bx = r & 63; by = (r >> 6) & 15;
  } else if (bid < 6144) {
    const int r = bid - 4096;
    const int lay = r >> 10;
    src = W2 + (size_t)lay * DFF_ * DM_;
    dst = wb + (size_t)lay * LSW_ + W2OFF_;
    K = DFF_; N = DM_; bx = r & 15; by = (r >> 4) & 63;
  } else {
    const int r = bid - 6144;
    const int lay = r >> 2;
    src = omg + (size_t)lay * DH_ * MF_;
    dst = omgTb + (size_t)lay * DH_ * MF_;
    K = DH_; N = MF_; bx = r & 1; by = (r >> 1) & 1;
  }
  const int n0 = bx * 32, k0 = by * 32;
  {  // vectorized load: row rl (k), 4 cols (n)
    const int c4 = t & 7, rl = t >> 3;
    f4 v = *(const f4*)(src + (size_t)(k0 + rl) * N + n0 + c4 * 4);
    tile[rl][c4 * 4 + 0] = f2b(v.x);
    tile[rl][c4 * 4 + 1] = f2b(v.y);
    tile[rl][c4 * 4 + 2] = f2b(v.z);
    tile[rl][c4 * 4 + 3] = f2b(v.w);
  }
  __syncthreads();
  {  // vectorized store: row rs (n), 4 consecutive k
    const int cs = t & 7, rs = t >> 3;
    us4 o;
    o.x = tile[cs * 4 + 0][rs];
    o.y = tile[cs * 4 + 1][rs];
    o.z = tile[cs * 4 + 2][rs];
    o.w = tile[cs * 4 + 3][rs];
    *(us4*)(dst + (size_t)(n0 + rs) * K + k0 + cs * 4) = o;
  }
}

// ---------------------------------------------------------------- MFMA GEMM (full-K, z-slice QKV)
template<bool OUT_BF16>
__global__ __launch_bounds__(256) void mgemm(
    const ushortT* __restrict__ A, const ushortT* __restrict__ Wt,
    const float* __restrict__ bq_, const float* __restrict__ bk_,
    const float* __restrict__ bv_,
    float* __restrict__ Cf, ushortT* __restrict__ Cb, int K, int N) {
  __shared__ ushortT sA[2][2048];
  __shared__ ushortT sB[2][2048];
  const int t = threadIdx.x;
  const int w = t >> 6, l = t & 63;
  const int wm = w >> 1, wn = w & 1;
  const int n0 = blockIdx.x * 64, m0 = blockIdx.y * 64;
  const int z = blockIdx.z;
  const ushortT* Wz = Wt + (size_t)z * K * N;
  const float* bias = (z == 0) ? bq_ : (z == 1 ? bk_ : bv_);

  const int rs = w * 16 + (l >> 2);
  const int qs = (l & 3) ^ ((rs >> 1) & 3);
  const ushortT* gA = A  + (size_t)(m0 + rs) * K + qs * 8;
  const ushortT* gB = Wz + (size_t)(n0 + rs) * K + qs * 8;

  const int Ra = wm * 32 + (l & 15);
  const int Rb = wn * 32 + (l & 15);
  const int qq = l >> 4;
  const int aoff = (Ra * 4 + (qq ^ ((Ra >> 1) & 3))) * 8;
  const int boff = (Rb * 4 + (qq ^ ((Rb >> 1) & 3))) * 8;

  f4 acc[2][2];
#pragma unroll
  for (int i = 0; i < 2; ++i)
#pragma unroll
    for (int j = 0; j < 2; ++j) acc[i][j] = (f4){0.f, 0.f, 0.f, 0.f};

  auto stage = [&](int buf, int ko) {
    __builtin_amdgcn_global_load_lds(
        (const __attribute__((address_space(1))) void*)(gA + ko),
        (__attribute__((address_space(3))) void*)(&sA[buf][w * 512]), 16, 0, 0);
    __builtin_amdgcn_global_load_lds(
        (const __attribute__((address_space(1))) void*)(gB + ko),
        (__attribute__((address_space(3))) void*)(&sB[buf][w * 512]), 16, 0, 0);
  };

  stage(0, 0);
  const int nk = K >> 5;
  for (int ks = 0; ks < nk; ++ks) {
    __syncthreads();
    if (ks + 1 < nk) stage((ks + 1) & 1, (ks + 1) * 32);
    const ushortT* pa = sA[ks & 1];
    const ushortT* pb = sB[ks & 1];
    s8 a0 = *(const s8*)(pa + aoff);
    s8 a1 = *(const s8*)(pa + aoff + 512);
    s8 b0 = *(const s8*)(pb + boff);
    s8 b1 = *(const s8*)(pb + boff + 512);
    acc[0][0] = __builtin_amdgcn_mfma_f32_16x16x32_bf16(a0, b0, acc[0][0], 0, 0, 0);
    acc[0][1] = __builtin_amdgcn_mfma_f32_16x16x32_bf16(a0, b1, acc[0][1], 0, 0, 0);
    acc[1][0] = __builtin_amdgcn_mfma_f32_16x16x32_bf16(a1, b0, acc[1][0], 0, 0, 0);
    acc[1][1] = __builtin_amdgcn_mfma_f32_16x16x32_bf16(a1, b1, acc[1][1], 0, 0, 0);
  }

  const size_t outz = (size_t)z * S_ * N;
  const int colb = n0 + wn * 32 + (l & 15);
  const int rowb = m0 + wm * 32 + ((l >> 4) << 2);
#pragma unroll
  for (int mt = 0; mt < 2; ++mt) {
#pragma unroll
    for (int nt = 0; nt < 2; ++nt) {
      const int c = colb + nt * 16;
      const float bv = bias[c];
#pragma unroll
      for (int r = 0; r < 4; ++r) {
        const int rr = rowb + mt * 16 + r;
        float v = acc[mt][nt][r] + bv;
        if (OUT_BF16) Cb[outz + (size_t)rr * N + c] = f2b(v);
        else          Cf[outz + (size_t)rr * N + c] = v;
      }
    }
  }
}

// ---------------------------------------------------------------- MFMA GEMM partial 64-tile (split-K)
__global__ __launch_bounds__(256) void mgemm_part(
    const ushortT* __restrict__ A, const ushortT* __restrict__ Wt,
    float* __restrict__ PS, int K, int N, int KS) {
  __shared__ ushortT sA[2][2048];
  __shared__ ushortT sB[2][2048];
  const int t = threadIdx.x;
  const int w = t >> 6, l = t & 63;
  const int wm = w >> 1, wn = w & 1;
  const int n0 = blockIdx.x * 64, m0 = blockIdx.y * 64;
  const int z = blockIdx.z;

  const int rs = w * 16 + (l >> 2);
  const int qs = (l & 3) ^ ((rs >> 1) & 3);
  const ushortT* gA = A  + (size_t)(m0 + rs) * K + z * KS + qs * 8;
  const ushortT* gB = Wt + (size_t)(n0 + rs) * K + z * KS + qs * 8;

  const int Ra = wm * 32 + (l & 15);
  const int Rb = wn * 32 + (l & 15);
  const int qq = l >> 4;
  const int aoff = (Ra * 4 + (qq ^ ((Ra >> 1) & 3))) * 8;
  const int boff = (Rb * 4 + (qq ^ ((Rb >> 1) & 3))) * 8;

  f4 acc[2][2];
#pragma unroll
  for (int i = 0; i < 2; ++i)
#pragma unroll
    for (int j = 0; j < 2; ++j) acc[i][j] = (f4){0.f, 0.f, 0.f, 0.f};

  auto stage = [&](int buf, int ko) {
    __builtin_amdgcn_global_load_lds(
        (const __attribute__((address_space(1))) void*)(gA + ko),
        (__attribute__((address_space(3))) void*)(&sA[buf][w * 512]), 16, 0, 0);
    __builtin_amdgcn_global_load_lds(
        (const __attribute__((address_space(1))) void*)(gB + ko),
        (__attribute__((address_space(3))) void*)(&sB[buf][w * 512]), 16, 0, 0);
  };

  stage(0, 0);
  const int nk = KS >> 5;
  for (int ks = 0; ks < nk; ++ks) {
    __syncthreads();
    if (ks + 1 < nk) stage((ks + 1) & 1, (ks + 1) * 32);
    const ushortT* pa = sA[ks & 1];
    const ushortT* pb = sB[ks & 1];
    s8 a0 = *(const s8*)(pa + aoff);
    s8 a1 = *(const s8*)(pa + aoff + 512);
    s8 b0 = *(const s8*)(pb + boff);
    s8 b1 = *(const s8*)(pb + boff + 512);
    acc[0][0] = __builtin_amdgcn_mfma_f32_16x16x32_bf16(a0, b0, acc[0][0], 0, 0, 0);
    acc[0][1] = __builtin_amdgcn_mfma_f32_16x16x32_bf16(a0, b1, acc[0][1], 0, 0, 0);
    acc[1][0] = __builtin_amdgcn_mfma_f32_16x16x32_bf16(a1, b0, acc[1][0], 0, 0, 0);
    acc[1][1] = __builtin_amdgcn_mfma_f32_16x16x32_bf16(a1, b1, acc[1][1], 0, 0, 0);
  }

  float* out = PS + (size_t)z * S_ * N;
  const int colb = n0 + wn * 32 + (l & 15);
  const int rowb = m0 + wm * 32 + ((l >> 4) << 2);
#pragma unroll
  for (int mt = 0; mt < 2; ++mt) {
#pragma unroll
    for (int nt = 0; nt < 2; ++nt) {
      const int c = colb + nt * 16;
#pragma unroll
      for (int r = 0; r < 4; ++r)
        out[(size_t)(rowb + mt * 16 + r) * N + c] = acc[mt][nt][r];
    }
  }
}

// ---------------------------------------------------------------- MFMA GEMM, 128x128 tile
template<bool FULL>
__global__ __launch_bounds__(256) void mgemm128(
    const ushortT* __restrict__ A, const ushortT* __restrict__ Wt,
    const float* __restrict__ bias, float* __restrict__ PS,
    ushortT* __restrict__ Cb, int K, int N, int KS) {
  __shared__ ushortT sA[2][4096];
  __shared__ ushortT sB[2][4096];
  const int t = threadIdx.x;
  const int w = t >> 6, l = t & 63, lr = l & 15, q = l >> 4;
  const int wm = w >> 1, wn = w & 1;
  const int n0 = blockIdx.x * 128, m0 = blockIdx.y * 128;
  const int z = blockIdx.z;

  const int s0 = w * 128 + l, s1 = s0 + 64;
  const int r0 = s0 >> 2, kq0 = (s0 & 3) ^ ((r0 >> 1) & 3);
  const int r1 = s1 >> 2, kq1 = (s1 & 3) ^ ((r1 >> 1) & 3);
  const ushortT* gA0 = A  + (size_t)(m0 + r0) * K + z * KS + kq0 * 8;
  const ushortT* gA1 = A  + (size_t)(m0 + r1) * K + z * KS + kq1 * 8;
  const ushortT* gB0 = Wt + (size_t)(n0 + r0) * K + z * KS + kq0 * 8;
  const ushortT* gB1 = Wt + (size_t)(n0 + r1) * K + z * KS + kq1 * 8;

  int aoff[4], boff[4];
#pragma unroll
  for (int i = 0; i < 4; ++i) {
    const int RA = wm * 64 + i * 16 + lr;
    const int RB = wn * 64 + i * 16 + lr;
    aoff[i] = (RA * 4 + (q ^ ((RA >> 1) & 3))) * 8;
    boff[i] = (RB * 4 + (q ^ ((RB >> 1) & 3))) * 8;
  }

  f4 acc[4][4];
#pragma unroll
  for (int i = 0; i < 4; ++i)
#pragma unroll
    for (int j = 0; j < 4; ++j) acc[i][j] = (f4){0.f, 0.f, 0.f, 0.f};

  auto stage = [&](int buf, int ko) {
    __builtin_amdgcn_global_load_lds(
        (const __attribute__((address_space(1))) void*)(gA0 + ko),
        (__attribute__((address_space(3))) void*)(&sA[buf][w * 1024]), 16, 0, 0);
    __builtin_amdgcn_global_load_lds(
        (const __attribute__((address_space(1))) void*)(gA1 + ko),
        (__attribute__((address_space(3))) void*)(&sA[buf][w * 1024 + 512]), 16, 0, 0);
    __builtin_amdgcn_global_load_lds(
        (const __attribute__((address_space(1))) void*)(gB0 + ko),
        (__attribute__((address_space(3))) void*)(&sB[buf][w * 1024]), 16, 0, 0);
    __builtin_amdgcn_global_load_lds(
        (const __attribute__((address_space(1))) void*)(gB1 + ko),
        (__attribute__((address_space(3))) void*)(&sB[buf][w * 1024 + 512]), 16, 0, 0);
  };

  stage(0, 0);
  const int nk = (FULL ? K : KS) >> 5;
  for (int ks = 0; ks < nk; ++ks) {
    __syncthreads();
    if (ks + 1 < nk) stage((ks + 1) & 1, (ks + 1) * 32);
    const ushortT* pa = sA[ks & 1];
    const ushortT* pb = sB[ks & 1];
    s8 a[4], b[4];
#pragma unroll
    for (int i = 0; i < 4; ++i) {
      a[i] = *(const s8*)(pa + aoff[i]);
      b[i] = *(const s8*)(pb + boff[i]);
    }
#pragma unroll
    for (int mt = 0; mt < 4; ++mt)
#pragma unroll
      for (int nt = 0; nt < 4; ++nt)
        acc[mt][nt] = __builtin_amdgcn_mfma_f32_16x16x32_bf16(a[mt], b[nt], acc[mt][nt], 0, 0, 0);
  }

  const int colb = n0 + wn * 64 + lr;
  const int rowb = m0 + wm * 64 + q * 4;
  if (FULL) {
#pragma unroll
    for (int nt = 0; nt < 4; ++nt) {
      const int c = colb + nt * 16;
      const float bv = bias[c];
#pragma unroll
      for (int mt = 0; mt < 4; ++mt) {
#pragma unroll
        for (int r = 0; r < 4; ++r) {
          const int rr = rowb + mt * 16 + r;
          Cb[(size_t)rr * N + c] = f2b(fmaxf(acc[mt][nt][r] + bv, 0.f));
        }
      }
    }
  } else {
    float* out = PS + (size_t)z * S_ * N;
#pragma unroll
    for (int mt = 0; mt < 4; ++mt)
#pragma unroll
      for (int nt = 0; nt < 4; ++nt) {
        const int c = colb + nt * 16;
#pragma unroll
        for (int r = 0; r < 4; ++r)
          out[(size_t)(rowb + mt * 16 + r) * N + c] = acc[mt][nt][r];
      }
  }
}

// ---------------------------------------------------------------- reduce splits + bias + res + LN
__global__ __launch_bounds__(256) void redln(const float* __restrict__ PS, int nsplit,
                                             const float* __restrict__ bias,
                                             const float* __restrict__ res,
                                             const float* __restrict__ g,
                                             const float* __restrict__ be,
                                             float* __restrict__ outF,
                                             ushortT* __restrict__ outB) {
  const int s = blockIdx.x, t = threadIdx.x;
  float v0 = bias[t] + res[(size_t)s * DM_ + t];
  float v1 = bias[t + 256] + res[(size_t)s * DM_ + 256 + t];
  for (int z = 0; z < nsplit; ++z) {
    const float* p = PS + (size_t)z * S_ * DM_ + (size_t)s * DM_;
    v0 += p[t];
    v1 += p[256 + t];
  }
  float sum = v0 + v1, sq = v0 * v0 + v1 * v1;
  for (int off = 32; off > 0; off >>= 1) {
    sum += __shfl_down(sum, off);
    sq += __shfl_down(sq, off);
  }
  __shared__ float ssum[4], ssq[4];
  __shared__ float smean, srstd;
  const int w = t >> 6;
  if ((t & 63) == 0) { ssum[w] = sum; ssq[w] = sq; }
  __syncthreads();
  if (t == 0) {
    float S1 = ssum[0] + ssum[1] + ssum[2] + ssum[3];
    float S2 = ssq[0] + ssq[1] + ssq[2] + ssq[3];
    float mu = S1 / DM_;
    smean = mu;
    srstd = rsqrtf(S2 / DM_ - mu * mu + LN_EPS_);
  }
  __syncthreads();
  const float mu = smean, rs = srstd;
  float o0 = (v0 - mu) * rs * g[t] + be[t];
  float o1 = (v1 - mu) * rs * g[256 + t] + be[256 + t];
  outF[(size_t)s * DM_ + t] = o0;
  outF[(size_t)s * DM_ + 256 + t] = o1;
  if (outB) {
    outB[(size_t)s * DM_ + t] = f2b(o0);
    outB[(size_t)s * DM_ + 256 + t] = f2b(o1);
  }
}

// ---------------------------------------------------------------- FAVOR+ split (z=0: q ; z=1: k+v)
__global__ __launch_bounds__(256) void favor_sp(const ushortT* __restrict__ qkv,
                                                const ushortT* __restrict__ omgT,
                                                ushortT* __restrict__ PQb,
                                                ushortT* __restrict__ PKb,
                                                float* __restrict__ KVcT,
                                                float* __restrict__ Kc) {
  const int c = blockIdx.x, h = blockIdx.y, z = blockIdx.z, t = threadIdx.x;
  const int w = t >> 6, l = t & 63, lr = l & 15, q = l >> 4;
  __shared__ ushortT xx[64 * 72];    // xq (z=0) or xk (z=1)
  __shared__ ushortT vT[64 * 72];    // z=1 only
  __shared__ ushortT omT[64 * 72];
  __shared__ ushortT pp[64 * 72];    // pq or pk
  __shared__ ushortT ppT[64 * 72];   // z=1: pkT
  __shared__ float nrm[64];

  const ushortT* xg = qkv + (z ? (size_t)S_ * DM_ : 0) + (size_t)(c * CT_) * DM_ + h * DH_;
  const ushortT* vg = qkv + 2 * (size_t)S_ * DM_ + (size_t)(c * CT_) * DM_ + h * DH_;

  for (int i = t; i < 512; i += 256) {
    const int s = i >> 3, seg = i & 7;
    *(s8*)&xx[s * 72 + seg * 8] = *(const s8*)(xg + (size_t)s * DM_ + seg * 8);
    *(s8*)&omT[s * 72 + seg * 8] = *(const s8*)(omgT + s * 64 + seg * 8);
    if (z) {
      s8 av = *(const s8*)(vg + (size_t)s * DM_ + seg * 8);
#pragma unroll
      for (int j = 0; j < 8; ++j) vT[(seg * 8 + j) * 72 + s] = (ushortT)av[j];
    }
  }
  __syncthreads();

  if (t < 64) {
    float a = 0.f;
#pragma unroll
    for (int seg = 0; seg < 8; ++seg) {
      s8 vv = *(const s8*)(xx + t * 72 + seg * 8);
#pragma unroll
      for (int j = 0; j < 8; ++j) {
        float f = bu2f((ushortT)vv[j]);
        a += f * f;
      }
    }
    nrm[t] = a;
  }
  __syncthreads();

  {  // phi = exp(gam*u - 0.0625*nrm)*0.125,  u = x @ omegaT^T
    const float gam = 0.35355339059327373f;
    const int s0 = w * 16;
    s8 a0 = *(const s8*)&xx[(s0 + lr) * 72 + q * 8];
    s8 a1 = *(const s8*)&xx[(s0 + lr) * 72 + 32 + q * 8];
#pragma unroll
    for (int mt = 0; mt < 4; ++mt) {
      s8 b0 = *(const s8*)&omT[(mt * 16 + lr) * 72 + q * 8];
      s8 b1 = *(const s8*)&omT[(mt * 16 + lr) * 72 + 32 + q * 8];
      f4 cu = (f4){0.f, 0.f, 0.f, 0.f};
      cu = __builtin_amdgcn_mfma_f32_16x16x32_bf16(a0, b0, cu, 0, 0, 0);
      cu = __builtin_amdgcn_mfma_f32_16x16x32_bf16(a1, b1, cu, 0, 0, 0);
#pragma unroll
      for (int r = 0; r < 4; ++r) {
        const int sr = s0 + q * 4 + r, mc = mt * 16 + lr;
        float v = expf(gam * cu[r] - 0.0625f * nrm[sr]) * 0.125f;
        ushortT hv = f2b(v);
        pp[sr * 72 + mc] = hv;
        if (z) ppT[mc * 72 + sr] = hv;
      }
    }
  }
  __syncthreads();

  if (z) {  // KVcT[d][m] = V^T @ PK ; Kc[m]
    const int d0 = w * 16;
    s8 a0 = *(const s8*)&vT[(d0 + lr) * 72 + q * 8];
    s8 a1 = *(const s8*)&vT[(d0 + lr) * 72 + 32 + q * 8];
    float* outb = KVcT + (size_t)(h * NC_ + c) * DH_ * MF_;
#pragma unroll
    for (int mt = 0; mt < 4; ++mt) {
      s8 b0 = *(const s8*)&ppT[(mt * 16 + lr) * 72 + q * 8];
      s8 b1 = *(const s8*)&ppT[(mt * 16 + lr) * 72 + 32 + q * 8];
      f4 cs = (f4){0.f, 0.f, 0.f, 0.f};
      cs = __builtin_amdgcn_mfma_f32_16x16x32_bf16(a0, b0, cs, 0, 0, 0);
      cs = __builtin_amdgcn_mfma_f32_16x16x32_bf16(a1, b1, cs, 0, 0, 0);
#pragma unroll
      for (int r = 0; r < 4; ++r)
        outb[(size_t)(d0 + q * 4 + r) * MF_ + mt * 16 + lr] = cs[r];
    }
    if (t < 64) {
      float s = 0.f;
#pragma unroll
      for (int seg = 0; seg < 8; ++seg) {
        s8 vv = *(const s8*)&ppT[t * 72 + seg * 8];
#pragma unroll
        for (int j = 0; j < 8; ++j) s += bu2f((ushortT)vv[j]);
      }
      Kc[(size_t)(h * NC_ + c) * MF_ + t] = s;
    }
  }
  ushortT* dst = z ? PKb : PQb;
  for (int i = t; i < 512; i += 256) {
    const int s = i >> 3, seg = i & 7;
    *(s8*)(dst + (size_t)(c * CT_ + s) * DM_ + h * MF_ + seg * 8) = *(const s8*)&pp[s * 72 + seg * 8];
  }
}

// ---------------------------------------------------------------- prefix scan (register-resident)
__global__ __launch_bounds__(256) void prefix2(float* __restrict__ KVc,
                                               float* __restrict__ Kc) {
  const int h = blockIdx.x, seg = blockIdx.y, t = threadIdx.x;
  if (seg < 16) {
    float* base = KVc + (size_t)h * NC_ * MF_ * DH_ + seg * 256 + t;
    float v[NC_];
#pragma unroll
    for (int c = 0; c < NC_; ++c) v[c] = base[(size_t)c * MF_ * DH_];
    float run = 0.f;
#pragma unroll
    for (int c = 0; c < NC_; ++c) {
      float tmp = v[c];
      base[(size_t)c * MF_ * DH_] = run;
      run += tmp;
    }
  } else if (t < MF_) {
    float* base = Kc + (size_t)h * NC_ * MF_ + t;
    float v[NC_];
#pragma unroll
    for (int c = 0; c < NC_; ++c) v[c] = base[(size_t)c * MF_];
    float run = 0.f;
#pragma unroll
    for (int c = 0; c < NC_; ++c) {
      float tmp = v[c];
      base[(size_t)c * MF_] = run;
      run += tmp;
    }
  }
}

// ---------------------------------------------------------------- attention out split (z = d-half)
// Both halves compute Tm and den (identical values); numT covers 32 d-rows/block.
__global__ __launch_bounds__(256) void attn_sp(const ushortT* __restrict__ PQ,
                                               const ushortT* __restrict__ PK,
                                               const ushortT* __restrict__ V,
                                               const float* __restrict__ KVcT,
                                               const float* __restrict__ Kc,
                                               ushortT* __restrict__ Aout) {
  const int cc = blockIdx.x, h = blockIdx.y, z = blockIdx.z, t = threadIdx.x;
  const int w = t >> 6, l = t & 63;
  const int lr = l & 15, q = l >> 4;

  __shared__ ushortT pqs[64 * 72];
  __shared__ ushortT pks[64 * 72];
  __shared__ ushortT tms[64 * 72];
  __shared__ ushortT vts[32 * 72];   // d-half of V^T
  __shared__ ushortT kvs[32 * 72];   // d-half of KV prefix
  __shared__ float dpart[256];
  __shared__ float den[64];

  for (int i = t; i < 512; i += 256) {
    const int s = i >> 3, seg = i & 7;
    *(s8*)&pqs[s * 72 + seg * 8] = *(const s8*)(PQ + (size_t)(cc * CT_ + s) * DM_ + h * MF_ + seg * 8);
    *(s8*)&pks[s * 72 + seg * 8] = *(const s8*)(PK + (size_t)(cc * CT_ + s) * DM_ + h * MF_ + seg * 8);
  }
  {  // vts: d-rows [z*32, z*32+32)
    const int s = t >> 2, segl = t & 3, seg = z * 4 + segl;
    s8 av = *(const s8*)(V + (size_t)(cc * CT_ + s) * DM_ + h * DH_ + seg * 8);
#pragma unroll
    for (int j = 0; j < 8; ++j) vts[(segl * 8 + j) * 72 + s] = (ushortT)av[j];
  }
  {  // kvs: d-rows [z*32, z*32+32)
    const int dl = t >> 3, seg = t & 7;
    const float* kr = KVcT + (size_t)((h * NC_ + cc) * DH_ + z * 32 + dl) * MF_ + seg * 8;
    f4 g0 = *(const f4*)kr;
    f4 g1 = *(const f4*)(kr + 4);
    u32* p = (u32*)&kvs[dl * 72 + seg * 8];
    p[0] = pk2(g0.x, g0.y); p[1] = pk2(g0.z, g0.w);
    p[2] = pk2(g1.x, g1.y); p[3] = pk2(g1.z, g1.w);
  }
  __syncthreads();

  // Tm = PQ @ PK^T, tril (full, duplicated across halves)
  {
    const int s0 = w * 16;
    s8 a0 = *(const s8*)&pqs[(s0 + lr) * 72 + q * 8];
    s8 a1 = *(const s8*)&pqs[(s0 + lr) * 72 + 32 + q * 8];
#pragma unroll
    for (int tb = 0; tb < 4; ++tb) {
      f4 c = (f4){0.f, 0.f, 0.f, 0.f};
      if (tb <= w) {
        s8 b0 = *(const s8*)&pks[(tb * 16 + lr) * 72 + q * 8];
        s8 b1 = *(const s8*)&pks[(tb * 16 + lr) * 72 + 32 + q * 8];
        c = __builtin_amdgcn_mfma_f32_16x16x32_bf16(a0, b0, c, 0, 0, 0);
        c = __builtin_amdgcn_mfma_f32_16x16x32_bf16(a1, b1, c, 0, 0, 0);
      }
#pragma unroll
      for (int r = 0; r < 4; ++r) {
        float v = c[r];
        if (tb == w && lr > q * 4 + r) v = 0.f;
        tms[(s0 + q * 4 + r) * 72 + tb * 16 + lr] = f2b(v);
      }
    }
  }
  __syncthreads();

  // den (duplicated, identical)
  {
    const int s = t >> 2, part = t & 3;
    float dp = 0.f;
    const u32* trow = (const u32*)&tms[s * 72 + part * 16];
#pragma unroll
    for (int j = 0; j < 8; ++j) {
      u32 u = trow[j];
      dp += bu2f((ushortT)(u & 0xffffu)) + bu2f((ushortT)(u >> 16));
    }
    const u32* qrow = (const u32*)&pqs[s * 72 + part * 16];
    const f4* kc4 = (const f4*)(Kc + (size_t)(h * NC_ + cc) * MF_ + part * 16);
#pragma unroll
    for (int j = 0; j < 4; ++j) {
      f4 b = kc4[j];
      u32 ua = qrow[2 * j], ub = qrow[2 * j + 1];
      dp += bu2f((ushortT)(ua & 0xffffu)) * b.x + bu2f((ushortT)(ua >> 16)) * b.y +
            bu2f((ushortT)(ub & 0xffffu)) * b.z + bu2f((ushortT)(ub >> 16)) * b.w;
    }
    dpart[t] = dp;
  }
  __syncthreads();
  if (t < 64)
    den[t] = dpart[4 * t] + dpart[4 * t + 1] + dpart[4 * t + 2] + dpart[4 * t + 3] + EPS_;
  __syncthreads();

  // numT for this d-half: wave = (dgrp = w&1, sbh = w>>1 covers sb {2*sbh, 2*sbh+1})
  {
    const int dgrp = w & 1, sbh = w >> 1;
    const int dl = dgrp * 16 + lr;               // local d-row in [0,32)
    s8 akv0 = *(const s8*)&kvs[dl * 72 + q * 8];
    s8 akv1 = *(const s8*)&kvs[dl * 72 + 32 + q * 8];
    s8 av0  = *(const s8*)&vts[dl * 72 + q * 8];
    s8 av1  = *(const s8*)&vts[dl * 72 + 32 + q * 8];
    const int dcol = h * DH_ + z * 32 + dgrp * 16;
#pragma unroll
    for (int sbi = 0; sbi < 2; ++sbi) {
      const int sb = sbh * 2 + sbi;
      const int srow = sb * 16 + lr;
      s8 bq0 = *(const s8*)&pqs[srow * 72 + q * 8];
      s8 bq1 = *(const s8*)&pqs[srow * 72 + 32 + q * 8];
      s8 bt0 = *(const s8*)&tms[srow * 72 + q * 8];
      s8 bt1 = *(const s8*)&tms[srow * 72 + 32 + q * 8];
      f4 c = (f4){0.f, 0.f, 0.f, 0.f};
      c = __builtin_amdgcn_mfma_f32_16x16x32_bf16(akv0, bq0, c, 0, 0, 0);
      c = __builtin_amdgcn_mfma_f32_16x16x32_bf16(akv1, bq1, c, 0, 0, 0);
      c = __builtin_amdgcn_mfma_f32_16x16x32_bf16(av0, bt0, c, 0, 0, 0);
      c = __builtin_amdgcn_mfma_f32_16x16x32_bf16(av1, bt1, c, 0, 0, 0);
      const float inv = 1.f / den[srow];
      u32x2 o;
      o.x = pk2(c[0] * inv, c[1] * inv);
      o.y = pk2(c[2] * inv, c[3] * inv);
      *(u32x2*)(Aout + (size_t)(cc * CT_ + srow) * DM_ + dcol + q * 4) = o;
    }
  }
}

// ---------------------------------------------------------------- launch
extern "C" void kernel_launch(void* const* d_in, const int* in_sizes, int n_in,
                              void* d_out, int out_size, void* d_ws, size_t ws_size,
                              hipStream_t stream) {
  const float* x    = (const float*)d_in[0];
  const float* Wq   = (const float*)d_in[1];
  const float* Wk   = (const float*)d_in[2];
  const float* Wv   = (const float*)d_in[3];
  const float* Wo   = (const float*)d_in[4];
  const float* W1   = (const float*)d_in[5];
  const float* W2   = (const float*)d_in[6];
  const float* bq   = (const float*)d_in[7];
  const float* bk   = (const float*)d_in[8];
  const float* bv   = (const float*)d_in[9];
  const float* bo   = (const float*)d_in[10];
  const float* b1   = (const float*)d_in[11];
  const float* b2   = (const float*)d_in[12];
  const float* g1   = (const float*)d_in[13];
  const float* be1  = (const float*)d_in[14];
  const float* g2   = (const float*)d_in[15];
  const float* be2  = (const float*)d_in[16];
  const float* omg  = (const float*)d_in[17];
  float* out = (float*)d_out;

  const size_t MB = 1048576;
  float* f    = (float*)d_ws;
  float* cur  = f;                 // [S,DM] fp32
  float* ln1  = f + 1 * MB;
  float* KVcb = f + 2 * MB;        // [H,NC,DH,MF]
  float* Kcb  = f + 3 * MB;
  float* PS   = f + 3 * MB + 16384;  // 4 x [S,DM] fp32

  ushortT* u    = (ushortT*)(f + 8 * MB);
  ushortT* curb = u;
  ushortT* qkb  = u + 1 * MB;      // [3][S,DM] q,k,v bf16
  ushortT* pqb  = u + 4 * MB;
  ushortT* pkb  = u + 5 * MB;
  ushortT* qbb  = u + 6 * MB;      // attn out bf16
  ushortT* ln1b = u + 7 * MB;
  ushortT* ffb  = u + 8 * MB;      // [S,DFF] bf16 (4M)
  ushortT* wb   = u + 12 * MB;     // transposed weights (2 x LSW_)
  ushortT* omgTb = wb + 2 * LSW_;

  tcast_all<<<10248, 256, 0, stream>>>(x, Wq, Wk, Wv, Wo, W1, W2, omg,
                                       cur, curb, wb, omgTb);

  const dim3 gQKV(DM_ / 64, S_ / 64, 3);
  const dim3 gWo(DM_ / 64, S_ / 64, 2);
  const dim3 gW1(DFF_ / 128, S_ / 128, 1);   // (16,16)
  const dim3 gW2(DM_ / 128, S_ / 128, 4);    // (4,16,4)
  const dim3 gFav(NC_, H_, 2);
  const dim3 gAtt(NC_, H_, 2);
  const dim3 gPre(H_, 17);

  for (int l = 0; l < L_; ++l) {
    const ushortT* wl = wb + (size_t)l * LSW_;
    const size_t bo512 = (size_t)l * DM_;
    const size_t boFF = (size_t)l * DFF_;

    mgemm<true><<<gQKV, 256, 0, stream>>>(
        curb, wl, bq + bo512, bk + bo512, bv + bo512, nullptr, qkb, DM_, DM_);

    favor_sp<<<gFav, 256, 0, stream>>>(qkb, omgTb + (size_t)l * DH_ * MF_,
                                       pqb, pkb, KVcb, Kcb);
    prefix2<<<gPre, 256, 0, stream>>>(KVcb, Kcb);
    attn_sp<<<gAtt, 256, 0, stream>>>(pqb, pkb, qkb + 2 * (size_t)S_ * DM_,
                                      KVcb, Kcb, qbb);

    mgemm_part<<<gWo, 256, 0, stream>>>(qbb, wl + WOOFF_, PS, DM_, DM_, 256);
    redln<<<S_, 256, 0, stream>>>(PS, 2, bo + bo512, cur, g1 + bo512, be1 + bo512, ln1, ln1b);

    mgemm128<true><<<gW1, 256, 0, stream>>>(
        ln1b, wl + W1OFF_, b1 + boFF, nullptr, ffb, DM_, DFF_, 0);

    mgemm128<false><<<gW2, 256, 0, stream>>>(
        ffb, wl + W2OFF_, nullptr, PS, nullptr, DFF_, DM_, 512);
    const bool last = (l == L_ - 1);
    redln<<<S_, 256, 0, stream>>>(PS, 4, b2 + bo512, ln1, g2 + bo512, be2 + bo512,
                                  last ? out : cur, last ? nullptr : curb);
  }
}